// Round 1
// baseline (751.232 us; speedup 1.0000x reference)
//
#include <hip/hip_runtime.h>
#include <math.h>

#define LV 21504
#define LQ 8192
#define BS 4
#define NHD 8
#define HD 32
#define DIM 256

// ---------------------------------------------------------------------------
// K1: v = value @ W_v + b_v, written directly into "view-transposed" layout:
//   vv[b][n][ start_l*32 + s*32 + d ]  where, per (b,n,level),
//   flat[i] = v[b, start_l + i/32, n, i%32]  and  vv[s][d] = flat[d*hw + s].
// Row tile = 32 rows strided by hw/32:  r = start + d*(hw/32) + m, d=0..31.
// Then output (row d, head n, chan c) lands at s = m*32 + c -> coalesced.
// ---------------------------------------------------------------------------
__global__ __launch_bounds__(256) void k_vproj(
    const float* __restrict__ value, const float* __restrict__ Wv,
    const float* __restrict__ bv, float* __restrict__ vv)
{
  __shared__ float lA[32][257];   // [row d][k], pad 257 -> conflict-free col reads
  __shared__ float lB[16][256];   // [kk][col]

  int bid = blockIdx.x;
  int b = bid / 672, rem = bid % 672;
  int l, m;
  if (rem < 512)      { l = 0; m = rem; }
  else if (rem < 640) { l = 1; m = rem - 512; }
  else                { l = 2; m = rem - 640; }
  const int startl[3] = {0, 16384, 20480};
  const int hwd[3]    = {512, 128, 32};
  int start = startl[l], hd32 = hwd[l];

  int t = threadIdx.x;
  const float* Ab = value + (size_t)b * LV * DIM;

  // Stage whole A tile: 32 rows x 256 k  (2048 float4s, 8 per thread)
  for (int j = 0; j < 8; ++j) {
    int fi = j * 256 + t;
    int d  = fi >> 6, kq = fi & 63;
    const float4 v4 = *(const float4*)(Ab + (size_t)(start + d * hd32 + m) * DIM + kq * 4);
    lA[d][kq*4+0] = v4.x; lA[d][kq*4+1] = v4.y;
    lA[d][kq*4+2] = v4.z; lA[d][kq*4+3] = v4.w;
  }

  float acc[32];
  #pragma unroll
  for (int j = 0; j < 32; ++j) acc[j] = 0.f;

  int d = t & 31;   // tile row  (= view-channel index)
  int g = t >> 5;   // head n
  for (int k0 = 0; k0 < 256; k0 += 16) {
    __syncthreads();
    for (int j = 0; j < 4; ++j) {               // stage B: 16 k-rows x 256 cols
      int fi = j * 256 + t;
      int kk = fi >> 6, kq = fi & 63;
      *(float4*)&lB[kk][kq*4] = *(const float4*)(Wv + (size_t)(k0 + kk) * DIM + kq * 4);
    }
    __syncthreads();
    for (int kk = 0; kk < 16; ++kk) {
      float a = lA[d][k0 + kk];
      #pragma unroll
      for (int j = 0; j < 8; ++j) {
        float4 bq = *(const float4*)&lB[kk][g*32 + j*4];
        acc[j*4+0] += a * bq.x; acc[j*4+1] += a * bq.y;
        acc[j*4+2] += a * bq.z; acc[j*4+3] += a * bq.w;
      }
    }
  }

  // epilogue: bias + scatter (coalesced across lanes: fixed j, d consecutive)
  float* vb = vv + ((size_t)(b * NHD + g) * LV + start) * 32;
  #pragma unroll
  for (int j = 0; j < 32; ++j) {
    float o = acc[j] + bv[g * 32 + j];
    vb[(size_t)(m * 32 + j) * 32 + d] = o;
  }
}

// ---------------------------------------------------------------------------
// K2: offattn[bq][0:192] = query@W_off + b_off ; [192:288] = query@W_attn + b_attn
// Tile 64 rows x 96 cols, K=256, thread = 4x6.
// ---------------------------------------------------------------------------
__global__ __launch_bounds__(256) void k_offattn(
    const float* __restrict__ query, const float* __restrict__ Woff,
    const float* __restrict__ boff, const float* __restrict__ Wattn,
    const float* __restrict__ battn, float* __restrict__ offattn)
{
  __shared__ float lA[64][33];
  __shared__ float lB[32][96];
  int r0 = blockIdx.x * 64;
  int c0 = blockIdx.y * 96;
  int t = threadIdx.x;
  int tx = t & 15, ty = t >> 4;
  float acc[4][6];
  #pragma unroll
  for (int i = 0; i < 4; ++i)
    #pragma unroll
    for (int j = 0; j < 6; ++j) acc[i][j] = 0.f;

  for (int k0 = 0; k0 < 256; k0 += 32) {
    __syncthreads();
    for (int j = 0; j < 2; ++j) {                 // A: 64 rows x 32 k
      int fi = j * 256 + t;
      int r = fi >> 3, kq = fi & 7;
      float4 v4 = *(const float4*)(query + (size_t)(r0 + r) * DIM + k0 + kq * 4);
      lA[r][kq*4+0] = v4.x; lA[r][kq*4+1] = v4.y;
      lA[r][kq*4+2] = v4.z; lA[r][kq*4+3] = v4.w;
    }
    for (int j = 0; j < 3; ++j) {                 // B: 32 k x 96 cols
      int fi = j * 256 + t;
      int kk = fi / 24, cq = fi % 24;
      int col = c0 + cq * 4;
      float4 v4;
      if (col < 192) v4 = *(const float4*)(Woff + (size_t)(k0 + kk) * 192 + col);
      else           v4 = *(const float4*)(Wattn + (size_t)(k0 + kk) * 96 + (col - 192));
      *(float4*)&lB[kk][cq*4] = v4;
    }
    __syncthreads();
    for (int kk = 0; kk < 32; ++kk) {
      float a_[4], b_[6];
      #pragma unroll
      for (int i = 0; i < 4; ++i) a_[i] = lA[ty*4+i][kk];
      #pragma unroll
      for (int j = 0; j < 6; ++j) b_[j] = lB[kk][tx*6+j];
      #pragma unroll
      for (int i = 0; i < 4; ++i)
        #pragma unroll
        for (int j = 0; j < 6; ++j) acc[i][j] += a_[i] * b_[j];
    }
  }
  for (int i = 0; i < 4; ++i) {
    int r = r0 + ty * 4 + i;
    for (int j = 0; j < 6; ++j) {
      int col = c0 + tx * 6 + j;
      float bias = (col < 192) ? boff[col] : battn[col - 192];
      offattn[(size_t)r * 288 + col] = acc[i][j] + bias;
    }
  }
}

// ---------------------------------------------------------------------------
// K3: sampler. Half-wave (32 lanes = 32 view-channels) per (b,q,head).
// Softmax over 12 logits (redundant per lane), 12 bilinear samples,
// 4 coalesced 128B gathers each, accumulate -> mid[bq][n*32+c].
// ---------------------------------------------------------------------------
__global__ __launch_bounds__(256) void k_sample(
    const float* __restrict__ offattn, const float* __restrict__ refp,
    const float* __restrict__ vv, float* __restrict__ mid)
{
  int e = blockIdx.x * 8 + (threadIdx.x >> 5);
  int c = threadIdx.x & 31;
  int n  = e & 7;
  int bq = e >> 3;                 // b*LQ + q
  int b  = bq >> 13;

  const float* oa = offattn + (size_t)bq * 288;
  float rx = refp[bq * 4 + 0], ry = refp[bq * 4 + 1];

  float lg[12];
  float mx = -1e30f;
  #pragma unroll
  for (int i = 0; i < 12; ++i) { lg[i] = oa[192 + n * 12 + i]; mx = fmaxf(mx, lg[i]); }
  float s = 0.f;
  #pragma unroll
  for (int i = 0; i < 12; ++i) { lg[i] = __expf(lg[i] - mx); s += lg[i]; }
  float inv = 1.f / s;

  const int startl[3] = {0, 16384, 20480};
  const int whl[3]    = {128, 64, 32};
  float acc = 0.f;
  const float* vbase = vv + (size_t)(b * NHD + n) * LV * 32;

  #pragma unroll
  for (int l = 0; l < 3; ++l) {
    int w = whl[l], h = whl[l];
    float fw = (float)w, fh = (float)h;
    const float* vb = vbase + (size_t)startl[l] * 32;
    #pragma unroll
    for (int p = 0; p < 4; ++p) {
      float ox = oa[n * 24 + (l * 4 + p) * 2 + 0];
      float oy = oa[n * 24 + (l * 4 + p) * 2 + 1];
      float aw = lg[l * 4 + p] * inv;
      float px = fminf(fmaxf(rx + ox, 0.f), 1.f);
      float py = fminf(fmaxf(ry + oy, 0.f), 1.f);
      float x = px * fw - 0.5f, y = py * fh - 0.5f;
      float x0f = floorf(x), y0f = floorf(y);
      int x0 = (int)x0f, y0 = (int)y0f;
      float wx1 = x - x0f, wy1 = y - y0f;
      float wx0 = 1.f - wx1, wy0 = 1.f - wy1;
      bool vx0 = (x0 >= 0) && (x0 < w);
      bool vx1 = (x0 + 1 >= 0) && (x0 + 1 < w);
      bool vy0 = (y0 >= 0) && (y0 < h);
      bool vy1 = (y0 + 1 >= 0) && (y0 + 1 < h);
      float smp = 0.f;
      int base00 = (y0 * w + x0) * 32 + c;
      if (vy0 && vx0) smp += wy0 * wx0 * vb[base00];
      if (vy0 && vx1) smp += wy0 * wx1 * vb[base00 + 32];
      if (vy1 && vx0) smp += wy1 * wx0 * vb[base00 + 32 * w];
      if (vy1 && vx1) smp += wy1 * wx1 * vb[base00 + 32 * w + 32];
      acc += aw * smp;
    }
  }
  mid[(size_t)bq * 256 + n * 32 + c] = acc;
}

// ---------------------------------------------------------------------------
// K4: out = mid @ W_out + b_out.  Tile 64x64, thread = 4x4.
// ---------------------------------------------------------------------------
__global__ __launch_bounds__(256) void k_out(
    const float* __restrict__ mid, const float* __restrict__ Wout,
    const float* __restrict__ bout, float* __restrict__ out)
{
  __shared__ float lA[64][33];
  __shared__ float lB[32][64];
  int r0 = blockIdx.x * 64, c0 = blockIdx.y * 64;
  int t = threadIdx.x, tx = t & 15, ty = t >> 4;
  float acc[4][4];
  #pragma unroll
  for (int i = 0; i < 4; ++i)
    #pragma unroll
    for (int j = 0; j < 4; ++j) acc[i][j] = 0.f;

  for (int k0 = 0; k0 < 256; k0 += 32) {
    __syncthreads();
    for (int j = 0; j < 2; ++j) {
      int fi = j * 256 + t;
      int r = fi >> 3, kq = fi & 7;
      float4 v4 = *(const float4*)(mid + (size_t)(r0 + r) * DIM + k0 + kq * 4);
      lA[r][kq*4+0] = v4.x; lA[r][kq*4+1] = v4.y;
      lA[r][kq*4+2] = v4.z; lA[r][kq*4+3] = v4.w;
    }
    for (int j = 0; j < 2; ++j) {
      int fi = j * 256 + t;
      int kk = fi >> 4, cq = fi & 15;
      *(float4*)&lB[kk][cq*4] = *(const float4*)(Wout + (size_t)(k0 + kk) * DIM + c0 + cq * 4);
    }
    __syncthreads();
    for (int kk = 0; kk < 32; ++kk) {
      float a_[4];
      float4 b4 = *(const float4*)&lB[kk][tx * 4];
      #pragma unroll
      for (int i = 0; i < 4; ++i) a_[i] = lA[ty*4+i][kk];
      #pragma unroll
      for (int i = 0; i < 4; ++i) {
        acc[i][0] += a_[i] * b4.x; acc[i][1] += a_[i] * b4.y;
        acc[i][2] += a_[i] * b4.z; acc[i][3] += a_[i] * b4.w;
      }
    }
  }
  for (int i = 0; i < 4; ++i) {
    int r = r0 + ty * 4 + i;
    for (int j = 0; j < 4; ++j) {
      int col = c0 + tx * 4 + j;
      out[(size_t)r * DIM + col] = acc[i][j] + bout[col];
    }
  }
}

extern "C" void kernel_launch(void* const* d_in, const int* in_sizes, int n_in,
                              void* d_out, int out_size, void* d_ws, size_t ws_size,
                              hipStream_t stream) {
  const float* query = (const float*)d_in[0];
  const float* refp  = (const float*)d_in[1];
  const float* value = (const float*)d_in[2];
  const float* Woff  = (const float*)d_in[3];
  const float* boff  = (const float*)d_in[4];
  const float* Wattn = (const float*)d_in[5];
  const float* battn = (const float*)d_in[6];
  const float* Wv    = (const float*)d_in[7];
  const float* bv    = (const float*)d_in[8];
  const float* Wout  = (const float*)d_in[9];
  const float* bout  = (const float*)d_in[10];
  float* out = (float*)d_out;

  float* ws      = (float*)d_ws;
  float* vv      = ws;                          // 22,020,096 floats (88 MB)
  float* offattn = ws + 22020096;               //  9,437,184 floats (37.7 MB)
  float* mid     = ws + 22020096 + 9437184;     //  8,388,608 floats (33.5 MB)

  hipLaunchKernelGGL(k_vproj,   dim3(2688),    dim3(256), 0, stream, value, Wv, bv, vv);
  hipLaunchKernelGGL(k_offattn, dim3(512, 3),  dim3(256), 0, stream, query, Woff, boff, Wattn, battn, offattn);
  hipLaunchKernelGGL(k_sample,  dim3(32768),   dim3(256), 0, stream, offattn, refp, vv, mid);
  hipLaunchKernelGGL(k_out,     dim3(512, 4),  dim3(256), 0, stream, mid, Wout, bout, out);
}

// Round 3
// 493.243 us; speedup vs baseline: 1.5230x; 1.5230x over previous
//
#include <hip/hip_runtime.h>
#include <math.h>

#define LV 21504
#define LQ 8192
#define BS 4
#define NHD 8
#define HD 32
#define DIM 256

typedef __attribute__((ext_vector_type(4))) float f32x4;
typedef __attribute__((ext_vector_type(8))) short s16x8;
typedef unsigned short ushort_t;
typedef unsigned int uint_t;

// round-to-nearest-even bf16 split: f ~= hi + lo (each bf16)
__device__ __forceinline__ void bsplit(float f, ushort_t& h, ushort_t& l) {
  uint_t u = __float_as_uint(f);
  uint_t hr = (u + 0x7fffu + ((u >> 16) & 1u)) >> 16;
  h = (ushort_t)hr;
  float fh = __uint_as_float(hr << 16);
  float fl = f - fh;
  uint_t v = __float_as_uint(fl);
  l = (ushort_t)((v + 0x7fffu + ((v >> 16) & 1u)) >> 16);
}

// ---------------------------------------------------------------------------
// K0: split+transpose weights into bf16 hi/lo fragment-friendly [col][k] form.
// Lives in d_out (ushort): Wvt_h [0,65536) Wvt_l [65536,131072)
//                          Wot_h [131072,204800) Wot_l [204800,278528)
// d_out is only overwritten by k_out (which doesn't read these) -> safe.
// ---------------------------------------------------------------------------
__global__ __launch_bounds__(256) void k_wsplit(
    const float* __restrict__ Wv, const float* __restrict__ Woff,
    const float* __restrict__ Wattn, ushort_t* __restrict__ wbuf)
{
  int c = blockIdx.x;      // 0..543
  int k = threadIdx.x;     // 0..255
  float w;
  ushort_t *dh, *dl;
  if (c < 256) {
    w = Wv[(size_t)k * 256 + c];
    dh = wbuf + (size_t)c * 256 + k;
    dl = wbuf + 65536 + (size_t)c * 256 + k;
  } else {
    int co = c - 256;      // 0..287
    w = (co < 192) ? Woff[(size_t)k * 192 + co] : Wattn[(size_t)k * 96 + (co - 192)];
    dh = wbuf + 131072 + (size_t)co * 256 + k;
    dl = wbuf + 204800 + (size_t)co * 256 + k;
  }
  ushort_t h, l;
  bsplit(w, h, l);
  *dh = h; *dl = l;
}

// ---------------------------------------------------------------------------
// K1: v = value @ W_v + b_v  ->  view-transposed vv, MFMA bf16x3.
// Block tile: M=64 (32 d x 2 m), N=256, K=256 in 8 steps of 32.
// 4 waves, each M64xN64 -> 16 acc frags.
// ---------------------------------------------------------------------------
__global__ __launch_bounds__(256, 3) void k_vproj(
    const float* __restrict__ value, const ushort_t* __restrict__ wbuf,
    const float* __restrict__ bv, float* __restrict__ vv)
{
  __shared__ ushort_t lAh[64][40];   // 80B row stride: conflict-free b128 reads
  __shared__ ushort_t lAl[64][40];

  int bid = blockIdx.x;
  int b = bid / 336, rem = bid % 336;
  int l, mp;
  if (rem < 256)      { l = 0; mp = rem; }
  else if (rem < 320) { l = 1; mp = rem - 256; }
  else                { l = 2; mp = rem - 320; }
  const int startl[3] = {0, 16384, 20480};
  const int hwd[3]    = {512, 128, 32};
  int start = startl[l], hd32 = hwd[l], m0 = mp * 2;

  int t = threadIdx.x;
  int wave = t >> 6, lane = t & 63;
  int l15 = lane & 15, l4 = lane >> 4;
  int n0 = wave * 64;

  const float* Ab = value + (size_t)b * LV * DIM;
  int row0 = t >> 3, kq = t & 7;          // unit i=0
  int row1 = row0 + 32;                   // unit i=1
  const float* ap0 = Ab + (size_t)(start + (row0 & 31) * hd32 + m0 + (row0 >> 5)) * DIM + kq * 4;
  const float* ap1 = Ab + (size_t)(start + (row1 & 31) * hd32 + m0 + (row1 >> 5)) * DIM + kq * 4;

  f32x4 acc[4][4];
  #pragma unroll
  for (int m = 0; m < 4; ++m)
    #pragma unroll
    for (int n = 0; n < 4; ++n) acc[m][n] = (f32x4){0.f, 0.f, 0.f, 0.f};

  for (int s = 0; s < 8; ++s) {
    int k0 = s * 32;
    // B fragments straight from L2-resident split tables
    s16x8 bh[4], bl[4];
    #pragma unroll
    for (int n = 0; n < 4; ++n) {
      int col = n0 + n * 16 + l15;
      bh[n] = *(const s16x8*)(wbuf + (size_t)col * 256 + k0 + l4 * 8);
      bl[n] = *(const s16x8*)(wbuf + 65536 + (size_t)col * 256 + k0 + l4 * 8);
    }
    // stage A (f32 -> split bf16 LDS)
    {
      float4 v0 = *(const float4*)(ap0 + k0);
      float4 v1 = *(const float4*)(ap1 + k0);
      float a0[4] = {v0.x, v0.y, v0.z, v0.w};
      float a1[4] = {v1.x, v1.y, v1.z, v1.w};
      ushort_t hh[4], ll[4];
      #pragma unroll
      for (int j = 0; j < 4; ++j) bsplit(a0[j], hh[j], ll[j]);
      *(uint_t*)&lAh[row0][kq * 4]     = (uint_t)hh[0] | ((uint_t)hh[1] << 16);
      *(uint_t*)&lAh[row0][kq * 4 + 2] = (uint_t)hh[2] | ((uint_t)hh[3] << 16);
      *(uint_t*)&lAl[row0][kq * 4]     = (uint_t)ll[0] | ((uint_t)ll[1] << 16);
      *(uint_t*)&lAl[row0][kq * 4 + 2] = (uint_t)ll[2] | ((uint_t)ll[3] << 16);
      #pragma unroll
      for (int j = 0; j < 4; ++j) bsplit(a1[j], hh[j], ll[j]);
      *(uint_t*)&lAh[row1][kq * 4]     = (uint_t)hh[0] | ((uint_t)hh[1] << 16);
      *(uint_t*)&lAh[row1][kq * 4 + 2] = (uint_t)hh[2] | ((uint_t)hh[3] << 16);
      *(uint_t*)&lAl[row1][kq * 4]     = (uint_t)ll[0] | ((uint_t)ll[1] << 16);
      *(uint_t*)&lAl[row1][kq * 4 + 2] = (uint_t)ll[2] | ((uint_t)ll[3] << 16);
    }
    __syncthreads();
    s16x8 ah[4], al[4];
    #pragma unroll
    for (int m = 0; m < 4; ++m) {
      ah[m] = *(const s16x8*)&lAh[m * 16 + l15][l4 * 8];
      al[m] = *(const s16x8*)&lAl[m * 16 + l15][l4 * 8];
    }
    #pragma unroll
    for (int n = 0; n < 4; ++n)
      #pragma unroll
      for (int m = 0; m < 4; ++m) {
        acc[m][n] = __builtin_amdgcn_mfma_f32_16x16x32_bf16(ah[m], bh[n], acc[m][n], 0, 0, 0);
        acc[m][n] = __builtin_amdgcn_mfma_f32_16x16x32_bf16(al[m], bh[n], acc[m][n], 0, 0, 0);
        acc[m][n] = __builtin_amdgcn_mfma_f32_16x16x32_bf16(ah[m], bl[n], acc[m][n], 0, 0, 0);
      }
    __syncthreads();
  }

  // epilogue: bias + scatter into view-transposed vv (16B stores)
  #pragma unroll
  for (int m = 0; m < 4; ++m) {
    int d = (m & 1) * 16 + l4 * 4;
    int mloc = m0 + (m >> 1);
    #pragma unroll
    for (int n = 0; n < 4; ++n) {
      int col = n0 + n * 16 + l15;
      int g = col >> 5, j = col & 31;
      float bias = bv[col];
      f32x4 o = acc[m][n];
      o[0] += bias; o[1] += bias; o[2] += bias; o[3] += bias;
      float* dst = vv + ((size_t)(b * NHD + g) * LV + start) * 32
                      + ((size_t)mloc * 32 + j) * 32 + d;
      *(f32x4*)dst = o;
    }
  }
}

// ---------------------------------------------------------------------------
// K2: offattn = query @ [W_off | W_attn] + bias.  M=64, N=288, 6 waves x 3 frags.
// ---------------------------------------------------------------------------
__global__ __launch_bounds__(384, 3) void k_offattn(
    const float* __restrict__ query, const ushort_t* __restrict__ wbuf,
    const float* __restrict__ boff, const float* __restrict__ battn,
    float* __restrict__ offattn)
{
  __shared__ ushort_t lAh[64][40];
  __shared__ ushort_t lAl[64][40];
  int r0 = blockIdx.x * 64;
  int t = threadIdx.x;
  int wave = t >> 6, lane = t & 63;
  int l15 = lane & 15, l4 = lane >> 4;
  int n0 = wave * 48;
  const ushort_t* wh = wbuf + 131072;
  const ushort_t* wl = wbuf + 204800;

  f32x4 acc[4][3];
  #pragma unroll
  for (int m = 0; m < 4; ++m)
    #pragma unroll
    for (int n = 0; n < 3; ++n) acc[m][n] = (f32x4){0.f, 0.f, 0.f, 0.f};

  for (int s = 0; s < 8; ++s) {
    int k0 = s * 32;
    s16x8 bh[3], bl[3];
    #pragma unroll
    for (int n = 0; n < 3; ++n) {
      int col = n0 + n * 16 + l15;
      bh[n] = *(const s16x8*)(wh + (size_t)col * 256 + k0 + l4 * 8);
      bl[n] = *(const s16x8*)(wl + (size_t)col * 256 + k0 + l4 * 8);
    }
    #pragma unroll
    for (int i = 0; i < 2; ++i) {
      int u = i * 384 + t;
      if (u < 512) {
        int row = u >> 3, kq = u & 7;
        float4 v = *(const float4*)(query + (size_t)(r0 + row) * DIM + k0 + kq * 4);
        float a0[4] = {v.x, v.y, v.z, v.w};
        ushort_t hh[4], ll[4];
        #pragma unroll
        for (int j = 0; j < 4; ++j) bsplit(a0[j], hh[j], ll[j]);
        *(uint_t*)&lAh[row][kq * 4]     = (uint_t)hh[0] | ((uint_t)hh[1] << 16);
        *(uint_t*)&lAh[row][kq * 4 + 2] = (uint_t)hh[2] | ((uint_t)hh[3] << 16);
        *(uint_t*)&lAl[row][kq * 4]     = (uint_t)ll[0] | ((uint_t)ll[1] << 16);
        *(uint_t*)&lAl[row][kq * 4 + 2] = (uint_t)ll[2] | ((uint_t)ll[3] << 16);
      }
    }
    __syncthreads();
    s16x8 ah[4], al[4];
    #pragma unroll
    for (int m = 0; m < 4; ++m) {
      ah[m] = *(const s16x8*)&lAh[m * 16 + l15][l4 * 8];
      al[m] = *(const s16x8*)&lAl[m * 16 + l15][l4 * 8];
    }
    #pragma unroll
    for (int n = 0; n < 3; ++n)
      #pragma unroll
      for (int m = 0; m < 4; ++m) {
        acc[m][n] = __builtin_amdgcn_mfma_f32_16x16x32_bf16(ah[m], bh[n], acc[m][n], 0, 0, 0);
        acc[m][n] = __builtin_amdgcn_mfma_f32_16x16x32_bf16(al[m], bh[n], acc[m][n], 0, 0, 0);
        acc[m][n] = __builtin_amdgcn_mfma_f32_16x16x32_bf16(ah[m], bl[n], acc[m][n], 0, 0, 0);
      }
    __syncthreads();
  }
  #pragma unroll
  for (int m = 0; m < 4; ++m)
    #pragma unroll
    for (int n = 0; n < 3; ++n) {
      int col = n0 + n * 16 + l15;
      float bias = (col < 192) ? boff[col] : battn[col - 192];
      #pragma unroll
      for (int i = 0; i < 4; ++i)
        offattn[(size_t)(r0 + m * 16 + l4 * 4 + i) * 288 + col] = acc[m][n][i] + bias;
    }
}

// ---------------------------------------------------------------------------
// K3: sampler (unchanged math) -> emits mid as packed bf16 hi|lo u32.
// ---------------------------------------------------------------------------
__global__ __launch_bounds__(256) void k_sample(
    const float* __restrict__ offattn, const float* __restrict__ refp,
    const float* __restrict__ vv, uint_t* __restrict__ midp)
{
  int e = blockIdx.x * 8 + (threadIdx.x >> 5);
  int c = threadIdx.x & 31;
  int n  = e & 7;
  int bq = e >> 3;
  int b  = bq >> 13;

  const float* oa = offattn + (size_t)bq * 288;
  float rx = refp[bq * 4 + 0], ry = refp[bq * 4 + 1];

  float lg[12];
  float mx = -1e30f;
  #pragma unroll
  for (int i = 0; i < 12; ++i) { lg[i] = oa[192 + n * 12 + i]; mx = fmaxf(mx, lg[i]); }
  float s = 0.f;
  #pragma unroll
  for (int i = 0; i < 12; ++i) { lg[i] = __expf(lg[i] - mx); s += lg[i]; }
  float inv = 1.f / s;

  const int startl[3] = {0, 16384, 20480};
  const int whl[3]    = {128, 64, 32};
  float acc = 0.f;
  const float* vbase = vv + (size_t)(b * NHD + n) * LV * 32;

  #pragma unroll
  for (int l = 0; l < 3; ++l) {
    int w = whl[l], h = whl[l];
    float fw = (float)w, fh = (float)h;
    const float* vb = vbase + (size_t)startl[l] * 32;
    #pragma unroll
    for (int p = 0; p < 4; ++p) {
      float ox = oa[n * 24 + (l * 4 + p) * 2 + 0];
      float oy = oa[n * 24 + (l * 4 + p) * 2 + 1];
      float aw = lg[l * 4 + p] * inv;
      float px = fminf(fmaxf(rx + ox, 0.f), 1.f);
      float py = fminf(fmaxf(ry + oy, 0.f), 1.f);
      float x = px * fw - 0.5f, y = py * fh - 0.5f;
      float x0f = floorf(x), y0f = floorf(y);
      int x0 = (int)x0f, y0 = (int)y0f;
      float wx1 = x - x0f, wy1 = y - y0f;
      float wx0 = 1.f - wx1, wy0 = 1.f - wy1;
      bool vx0 = (x0 >= 0) && (x0 < w);
      bool vx1 = (x0 + 1 >= 0) && (x0 + 1 < w);
      bool vy0 = (y0 >= 0) && (y0 < h);
      bool vy1 = (y0 + 1 >= 0) && (y0 + 1 < h);
      float smp = 0.f;
      int base00 = (y0 * w + x0) * 32 + c;
      if (vy0 && vx0) smp += wy0 * wx0 * vb[base00];
      if (vy0 && vx1) smp += wy0 * wx1 * vb[base00 + 32];
      if (vy1 && vx0) smp += wy1 * wx0 * vb[base00 + 32 * w];
      if (vy1 && vx1) smp += wy1 * wx1 * vb[base00 + 32 * w + 32];
      acc += aw * smp;
    }
  }
  ushort_t h16, l16;
  bsplit(acc, h16, l16);
  midp[(size_t)bq * 256 + n * 32 + c] = (uint_t)h16 | ((uint_t)l16 << 16);
}

// ---------------------------------------------------------------------------
// K4: out = mid @ W_out + b_out. A pre-split (packed), B split on the fly.
// ---------------------------------------------------------------------------
__global__ __launch_bounds__(256, 3) void k_out(
    const uint_t* __restrict__ midp, const float* __restrict__ Wout,
    const float* __restrict__ bout, float* __restrict__ out)
{
  __shared__ ushort_t lAh[64][40];
  __shared__ ushort_t lAl[64][40];
  int r0 = blockIdx.x * 64;
  int t = threadIdx.x;
  int wave = t >> 6, lane = t & 63;
  int l15 = lane & 15, l4 = lane >> 4;
  int n0 = wave * 64;

  f32x4 acc[4][4];
  #pragma unroll
  for (int m = 0; m < 4; ++m)
    #pragma unroll
    for (int n = 0; n < 4; ++n) acc[m][n] = (f32x4){0.f, 0.f, 0.f, 0.f};

  for (int s = 0; s < 8; ++s) {
    int k0 = s * 32;
    s16x8 bh[4], bl[4];
    #pragma unroll
    for (int n = 0; n < 4; ++n) {
      int col = n0 + n * 16 + l15;
      #pragma unroll
      for (int j = 0; j < 8; ++j) {
        float w = Wout[(size_t)(k0 + l4 * 8 + j) * DIM + col];
        ushort_t h, lo;
        bsplit(w, h, lo);
        bh[n][j] = (short)h;
        bl[n][j] = (short)lo;
      }
    }
    #pragma unroll
    for (int i = 0; i < 2; ++i) {
      int u = i * 256 + t;
      int row = u >> 3, kq = u & 7;
      uint4 v = *(const uint4*)(midp + (size_t)(r0 + row) * DIM + k0 + kq * 4);
      uint_t a0 = v.x, a1 = v.y, a2 = v.z, a3 = v.w;
      *(uint_t*)&lAh[row][kq * 4]     = (a0 & 0xffffu) | ((a1 & 0xffffu) << 16);
      *(uint_t*)&lAh[row][kq * 4 + 2] = (a2 & 0xffffu) | ((a3 & 0xffffu) << 16);
      *(uint_t*)&lAl[row][kq * 4]     = (a0 >> 16) | (a1 & 0xffff0000u);
      *(uint_t*)&lAl[row][kq * 4 + 2] = (a2 >> 16) | (a3 & 0xffff0000u);
    }
    __syncthreads();
    s16x8 ah[4], al[4];
    #pragma unroll
    for (int m = 0; m < 4; ++m) {
      ah[m] = *(const s16x8*)&lAh[m * 16 + l15][l4 * 8];
      al[m] = *(const s16x8*)&lAl[m * 16 + l15][l4 * 8];
    }
    #pragma unroll
    for (int n = 0; n < 4; ++n)
      #pragma unroll
      for (int m = 0; m < 4; ++m) {
        acc[m][n] = __builtin_amdgcn_mfma_f32_16x16x32_bf16(ah[m], bh[n], acc[m][n], 0, 0, 0);
        acc[m][n] = __builtin_amdgcn_mfma_f32_16x16x32_bf16(al[m], bh[n], acc[m][n], 0, 0, 0);
        acc[m][n] = __builtin_amdgcn_mfma_f32_16x16x32_bf16(ah[m], bl[n], acc[m][n], 0, 0, 0);
      }
    __syncthreads();
  }
  #pragma unroll
  for (int m = 0; m < 4; ++m)
    #pragma unroll
    for (int n = 0; n < 4; ++n) {
      int col = n0 + n * 16 + l15;
      float bias = bout[col];
      #pragma unroll
      for (int i = 0; i < 4; ++i)
        out[(size_t)(r0 + m * 16 + l4 * 4 + i) * DIM + col] = acc[m][n][i] + bias;
    }
}

extern "C" void kernel_launch(void* const* d_in, const int* in_sizes, int n_in,
                              void* d_out, int out_size, void* d_ws, size_t ws_size,
                              hipStream_t stream) {
  const float* query = (const float*)d_in[0];
  const float* refp  = (const float*)d_in[1];
  const float* value = (const float*)d_in[2];
  const float* Woff  = (const float*)d_in[3];
  const float* boff  = (const float*)d_in[4];
  const float* Wattn = (const float*)d_in[5];
  const float* battn = (const float*)d_in[6];
  const float* Wv    = (const float*)d_in[7];
  const float* bv    = (const float*)d_in[8];
  const float* Wout  = (const float*)d_in[9];
  const float* bout  = (const float*)d_in[10];
  float* out = (float*)d_out;
  ushort_t* wbuf = (ushort_t*)d_out;    // split tables; overwritten only by k_out

  float* ws      = (float*)d_ws;
  float* vv      = ws;                                  // 22,020,096 f (88 MB)
  float* offattn = ws + 22020096;                       //  9,437,184 f (37.7 MB)
  uint_t* midp   = (uint_t*)(ws + 22020096 + 9437184);  //  8,388,608 u32 (33.5 MB)

  hipLaunchKernelGGL(k_wsplit,  dim3(544),   dim3(256), 0, stream, Wv, Woff, Wattn, wbuf);
  hipLaunchKernelGGL(k_vproj,   dim3(1344),  dim3(256), 0, stream, value, wbuf, bv, vv);
  hipLaunchKernelGGL(k_offattn, dim3(512),   dim3(384), 0, stream, query, wbuf, boff, battn, offattn);
  hipLaunchKernelGGL(k_sample,  dim3(32768), dim3(256), 0, stream, offattn, refp, vv, midp);
  hipLaunchKernelGGL(k_out,     dim3(512),   dim3(256), 0, stream, midp, Wout, bout, out);
}

// Round 5
// 353.774 us; speedup vs baseline: 2.1235x; 1.3942x over previous
//
#include <hip/hip_runtime.h>
#include <math.h>

#define LV 21504
#define LQ 8192
#define BS 4
#define NHD 8
#define HD 32
#define DIM 256

typedef __attribute__((ext_vector_type(4))) float f32x4;
typedef __attribute__((ext_vector_type(8))) short s16x8;
typedef unsigned short ushort_t;
typedef unsigned int uint_t;

// round-to-nearest-even bf16 split: f ~= hi + lo (each bf16)
__device__ __forceinline__ void bsplit(float f, ushort_t& h, ushort_t& l) {
  uint_t u = __float_as_uint(f);
  uint_t hr = (u + 0x7fffu + ((u >> 16) & 1u)) >> 16;
  h = (ushort_t)hr;
  float fh = __uint_as_float(hr << 16);
  float fl = f - fh;
  uint_t v = __float_as_uint(fl);
  l = (ushort_t)((v + 0x7fffu + ((v >> 16) & 1u)) >> 16);
}

// ---------------------------------------------------------------------------
// K0: split+transpose Wv / Woffattn into bf16 hi/lo [col][k] tables in d_out.
// d_out region is dead for these tables once vproj+offattn have run.
// ---------------------------------------------------------------------------
__global__ __launch_bounds__(256) void k_wsplit(
    const float* __restrict__ Wv, const float* __restrict__ Woff,
    const float* __restrict__ Wattn, ushort_t* __restrict__ wbuf)
{
  int c = blockIdx.x;      // 0..543
  int k = threadIdx.x;     // 0..255
  float w;
  ushort_t *dh, *dl;
  if (c < 256) {
    w = Wv[(size_t)k * 256 + c];
    dh = wbuf + (size_t)c * 256 + k;
    dl = wbuf + 65536 + (size_t)c * 256 + k;
  } else {
    int co = c - 256;      // 0..287
    w = (co < 192) ? Woff[(size_t)k * 192 + co] : Wattn[(size_t)k * 96 + (co - 192)];
    dh = wbuf + 131072 + (size_t)co * 256 + k;
    dl = wbuf + 204800 + (size_t)co * 256 + k;
  }
  ushort_t h, l;
  bsplit(w, h, l);
  *dh = h; *dl = l;
}

// K0b: split Wout into tables in the vv region (dead after k_sample).
__global__ __launch_bounds__(256) void k_wsplit2(
    const float* __restrict__ Wout, ushort_t* __restrict__ tb)
{
  int c = blockIdx.x;      // 0..255
  int k = threadIdx.x;     // 0..255
  float w = Wout[(size_t)k * 256 + c];
  ushort_t h, l;
  bsplit(w, h, l);
  tb[(size_t)c * 256 + k] = h;
  tb[65536 + (size_t)c * 256 + k] = l;
}

// ---------------------------------------------------------------------------
// K1: v = value @ W_v + b_v  ->  view-transposed vv, MFMA bf16x3.
// ---------------------------------------------------------------------------
__global__ __launch_bounds__(256, 3) void k_vproj(
    const float* __restrict__ value, const ushort_t* __restrict__ wbuf,
    const float* __restrict__ bv, float* __restrict__ vv)
{
  __shared__ ushort_t lAh[64][40];   // 80B row stride: conflict-free b128 reads
  __shared__ ushort_t lAl[64][40];

  int bid = blockIdx.x;
  int b = bid / 336, rem = bid % 336;
  int l, mp;
  if (rem < 256)      { l = 0; mp = rem; }
  else if (rem < 320) { l = 1; mp = rem - 256; }
  else                { l = 2; mp = rem - 320; }
  const int startl[3] = {0, 16384, 20480};
  const int hwd[3]    = {512, 128, 32};
  int start = startl[l], hd32 = hwd[l], m0 = mp * 2;

  int t = threadIdx.x;
  int wave = t >> 6, lane = t & 63;
  int l15 = lane & 15, l4 = lane >> 4;
  int n0 = wave * 64;

  const float* Ab = value + (size_t)b * LV * DIM;
  int row0 = t >> 3, kq = t & 7;
  int row1 = row0 + 32;
  const float* ap0 = Ab + (size_t)(start + (row0 & 31) * hd32 + m0 + (row0 >> 5)) * DIM + kq * 4;
  const float* ap1 = Ab + (size_t)(start + (row1 & 31) * hd32 + m0 + (row1 >> 5)) * DIM + kq * 4;

  f32x4 acc[4][4];
  #pragma unroll
  for (int m = 0; m < 4; ++m)
    #pragma unroll
    for (int n = 0; n < 4; ++n) acc[m][n] = (f32x4){0.f, 0.f, 0.f, 0.f};

  for (int s = 0; s < 8; ++s) {
    int k0 = s * 32;
    s16x8 bh[4], bl[4];
    #pragma unroll
    for (int n = 0; n < 4; ++n) {
      int col = n0 + n * 16 + l15;
      bh[n] = *(const s16x8*)(wbuf + (size_t)col * 256 + k0 + l4 * 8);
      bl[n] = *(const s16x8*)(wbuf + 65536 + (size_t)col * 256 + k0 + l4 * 8);
    }
    {
      float4 v0 = *(const float4*)(ap0 + k0);
      float4 v1 = *(const float4*)(ap1 + k0);
      float a0[4] = {v0.x, v0.y, v0.z, v0.w};
      float a1[4] = {v1.x, v1.y, v1.z, v1.w};
      ushort_t hh[4], ll[4];
      #pragma unroll
      for (int j = 0; j < 4; ++j) bsplit(a0[j], hh[j], ll[j]);
      *(uint_t*)&lAh[row0][kq * 4]     = (uint_t)hh[0] | ((uint_t)hh[1] << 16);
      *(uint_t*)&lAh[row0][kq * 4 + 2] = (uint_t)hh[2] | ((uint_t)hh[3] << 16);
      *(uint_t*)&lAl[row0][kq * 4]     = (uint_t)ll[0] | ((uint_t)ll[1] << 16);
      *(uint_t*)&lAl[row0][kq * 4 + 2] = (uint_t)ll[2] | ((uint_t)ll[3] << 16);
      #pragma unroll
      for (int j = 0; j < 4; ++j) bsplit(a1[j], hh[j], ll[j]);
      *(uint_t*)&lAh[row1][kq * 4]     = (uint_t)hh[0] | ((uint_t)hh[1] << 16);
      *(uint_t*)&lAh[row1][kq * 4 + 2] = (uint_t)hh[2] | ((uint_t)hh[3] << 16);
      *(uint_t*)&lAl[row1][kq * 4]     = (uint_t)ll[0] | ((uint_t)ll[1] << 16);
      *(uint_t*)&lAl[row1][kq * 4 + 2] = (uint_t)ll[2] | ((uint_t)ll[3] << 16);
    }
    __syncthreads();
    s16x8 ah[4], al[4];
    #pragma unroll
    for (int m = 0; m < 4; ++m) {
      ah[m] = *(const s16x8*)&lAh[m * 16 + l15][l4 * 8];
      al[m] = *(const s16x8*)&lAl[m * 16 + l15][l4 * 8];
    }
    #pragma unroll
    for (int n = 0; n < 4; ++n)
      #pragma unroll
      for (int m = 0; m < 4; ++m) {
        acc[m][n] = __builtin_amdgcn_mfma_f32_16x16x32_bf16(ah[m], bh[n], acc[m][n], 0, 0, 0);
        acc[m][n] = __builtin_amdgcn_mfma_f32_16x16x32_bf16(al[m], bh[n], acc[m][n], 0, 0, 0);
        acc[m][n] = __builtin_amdgcn_mfma_f32_16x16x32_bf16(ah[m], bl[n], acc[m][n], 0, 0, 0);
      }
    __syncthreads();
  }

  #pragma unroll
  for (int m = 0; m < 4; ++m) {
    int d = (m & 1) * 16 + l4 * 4;
    int mloc = m0 + (m >> 1);
    #pragma unroll
    for (int n = 0; n < 4; ++n) {
      int col = n0 + n * 16 + l15;
      int g = col >> 5, j = col & 31;
      float bias = bv[col];
      f32x4 o = acc[m][n];
      o[0] += bias; o[1] += bias; o[2] += bias; o[3] += bias;
      float* dst = vv + ((size_t)(b * NHD + g) * LV + start) * 32
                      + ((size_t)mloc * 32 + j) * 32 + d;
      *(f32x4*)dst = o;
    }
  }
}

// ---------------------------------------------------------------------------
// K2: offattn = query @ [W_off | W_attn] + bias.
// ---------------------------------------------------------------------------
__global__ __launch_bounds__(384, 3) void k_offattn(
    const float* __restrict__ query, const ushort_t* __restrict__ wbuf,
    const float* __restrict__ boff, const float* __restrict__ battn,
    float* __restrict__ offattn)
{
  __shared__ ushort_t lAh[64][40];
  __shared__ ushort_t lAl[64][40];
  int r0 = blockIdx.x * 64;
  int t = threadIdx.x;
  int wave = t >> 6, lane = t & 63;
  int l15 = lane & 15, l4 = lane >> 4;
  int n0 = wave * 48;
  const ushort_t* wh = wbuf + 131072;
  const ushort_t* wl = wbuf + 204800;

  f32x4 acc[4][3];
  #pragma unroll
  for (int m = 0; m < 4; ++m)
    #pragma unroll
    for (int n = 0; n < 3; ++n) acc[m][n] = (f32x4){0.f, 0.f, 0.f, 0.f};

  for (int s = 0; s < 8; ++s) {
    int k0 = s * 32;
    s16x8 bh[3], bl[3];
    #pragma unroll
    for (int n = 0; n < 3; ++n) {
      int col = n0 + n * 16 + l15;
      bh[n] = *(const s16x8*)(wh + (size_t)col * 256 + k0 + l4 * 8);
      bl[n] = *(const s16x8*)(wl + (size_t)col * 256 + k0 + l4 * 8);
    }
    #pragma unroll
    for (int i = 0; i < 2; ++i) {
      int u = i * 384 + t;
      if (u < 512) {
        int row = u >> 3, kq = u & 7;
        float4 v = *(const float4*)(query + (size_t)(r0 + row) * DIM + k0 + kq * 4);
        float a0[4] = {v.x, v.y, v.z, v.w};
        ushort_t hh[4], ll[4];
        #pragma unroll
        for (int j = 0; j < 4; ++j) bsplit(a0[j], hh[j], ll[j]);
        *(uint_t*)&lAh[row][kq * 4]     = (uint_t)hh[0] | ((uint_t)hh[1] << 16);
        *(uint_t*)&lAh[row][kq * 4 + 2] = (uint_t)hh[2] | ((uint_t)hh[3] << 16);
        *(uint_t*)&lAl[row][kq * 4]     = (uint_t)ll[0] | ((uint_t)ll[1] << 16);
        *(uint_t*)&lAl[row][kq * 4 + 2] = (uint_t)ll[2] | ((uint_t)ll[3] << 16);
      }
    }
    __syncthreads();
    s16x8 ah[4], al[4];
    #pragma unroll
    for (int m = 0; m < 4; ++m) {
      ah[m] = *(const s16x8*)&lAh[m * 16 + l15][l4 * 8];
      al[m] = *(const s16x8*)&lAl[m * 16 + l15][l4 * 8];
    }
    #pragma unroll
    for (int n = 0; n < 3; ++n)
      #pragma unroll
      for (int m = 0; m < 4; ++m) {
        acc[m][n] = __builtin_amdgcn_mfma_f32_16x16x32_bf16(ah[m], bh[n], acc[m][n], 0, 0, 0);
        acc[m][n] = __builtin_amdgcn_mfma_f32_16x16x32_bf16(al[m], bh[n], acc[m][n], 0, 0, 0);
        acc[m][n] = __builtin_amdgcn_mfma_f32_16x16x32_bf16(ah[m], bl[n], acc[m][n], 0, 0, 0);
      }
    __syncthreads();
  }
  #pragma unroll
  for (int m = 0; m < 4; ++m)
    #pragma unroll
    for (int n = 0; n < 3; ++n) {
      int col = n0 + n * 16 + l15;
      float bias = (col < 192) ? boff[col] : battn[col - 192];
      #pragma unroll
      for (int i = 0; i < 4; ++i)
        offattn[(size_t)(r0 + m * 16 + l4 * 4 + i) * 288 + col] = acc[m][n][i] + bias;
    }
}

// ---------------------------------------------------------------------------
// K3: sampler, 3-phase. Block = 64 items ((b,q,head) tuples).
//  A0: softmax stats (4 lanes/item, shfl reduce)
//  A : one thread per (item,point): combined weights + clamped byte offsets
//  B : 8 lanes/item, float4 channels: 4 gathers + 16 FMA per point
// ---------------------------------------------------------------------------
__global__ __launch_bounds__(256) void k_sample(
    const float* __restrict__ offattn, const float* __restrict__ refp,
    const float* __restrict__ vv, uint_t* __restrict__ midp)
{
  __shared__ float4 metaw[64][13];   // [item][point] combined corner weights
  __shared__ uint4  metaa[64][13];   // [item][point] corner byte offsets
  __shared__ float  smx[64], sinv[64];

  int t = threadIdx.x;
  int e0 = blockIdx.x * 64;

  // ---- A0 ----
  {
    int it = t >> 2, j = t & 3;
    int e = e0 + it;
    int n = e & 7, bq = e >> 3;
    const float* lgp = offattn + (size_t)bq * 288 + 192 + n * 12;
    float l0 = lgp[j], l1 = lgp[j + 4], l2 = lgp[j + 8];
    float m = fmaxf(fmaxf(l0, l1), l2);
    m = fmaxf(m, __shfl_xor(m, 1));
    m = fmaxf(m, __shfl_xor(m, 2));
    float s = __expf(l0 - m) + __expf(l1 - m) + __expf(l2 - m);
    s += __shfl_xor(s, 1);
    s += __shfl_xor(s, 2);
    if (j == 0) { smx[it] = m; sinv[it] = 1.f / s; }
  }
  __syncthreads();

  // ---- A ----
  const int startl[3] = {0, 16384, 20480};
  const int whl[3]    = {128, 64, 32};
  #pragma unroll
  for (int r = 0; r < 3; ++r) {
    int task = r * 256 + t;          // 0..767
    int it = task / 12, p = task % 12;
    int e = e0 + it;
    int n = e & 7, bq = e >> 3;
    int l = p >> 2;
    int w = whl[l], h = w;
    float fw = (float)w;
    const float* oa = offattn + (size_t)bq * 288;
    float ox = oa[n * 24 + p * 2], oy = oa[n * 24 + p * 2 + 1];
    float lg = oa[192 + n * 12 + p];
    float aw = __expf(lg - smx[it]) * sinv[it];
    float rx = refp[bq * 4], ry = refp[bq * 4 + 1];
    float px = fminf(fmaxf(rx + ox, 0.f), 1.f);
    float py = fminf(fmaxf(ry + oy, 0.f), 1.f);
    float x = px * fw - 0.5f, y = py * fw - 0.5f;
    float x0f = floorf(x), y0f = floorf(y);
    int x0 = (int)x0f, y0 = (int)y0f;
    float wx1 = x - x0f, wy1 = y - y0f;
    float wx0 = 1.f - wx1, wy0 = 1.f - wy1;
    float vx0 = ((uint_t)x0 < (uint_t)w) ? 1.f : 0.f;
    float vx1 = ((uint_t)(x0 + 1) < (uint_t)w) ? 1.f : 0.f;
    float vy0 = ((uint_t)y0 < (uint_t)h) ? 1.f : 0.f;
    float vy1 = ((uint_t)(y0 + 1) < (uint_t)h) ? 1.f : 0.f;
    int xc0 = min(max(x0, 0), w - 1), xc1 = min(max(x0 + 1, 0), w - 1);
    int yc0 = min(max(y0, 0), h - 1), yc1 = min(max(y0 + 1, 0), h - 1);
    int s0 = startl[l];
    uint4 av;
    av.x = (uint_t)(s0 + yc0 * w + xc0) * 128u;
    av.y = (uint_t)(s0 + yc0 * w + xc1) * 128u;
    av.z = (uint_t)(s0 + yc1 * w + xc0) * 128u;
    av.w = (uint_t)(s0 + yc1 * w + xc1) * 128u;
    float4 wv;
    wv.x = aw * wy0 * wx0 * vy0 * vx0;
    wv.y = aw * wy0 * wx1 * vy0 * vx1;
    wv.z = aw * wy1 * wx0 * vy1 * vx0;
    wv.w = aw * wy1 * wx1 * vy1 * vx1;
    metaw[it][p] = wv;
    metaa[it][p] = av;
  }
  __syncthreads();

  // ---- B ----
  #pragma unroll
  for (int r = 0; r < 2; ++r) {
    int it = (t >> 3) + r * 32;
    int c4 = t & 7;
    int e = e0 + it;
    int n = e & 7, bq = e >> 3, b = bq >> 13;
    const char* vb = (const char*)(vv + (size_t)(b * NHD + n) * LV * 32) + c4 * 16;
    f32x4 acc = (f32x4){0.f, 0.f, 0.f, 0.f};
    #pragma unroll
    for (int p = 0; p < 12; ++p) {
      float4 wv = metaw[it][p];
      uint4  av = metaa[it][p];
      f32x4 g00 = *(const f32x4*)(vb + av.x);
      f32x4 g01 = *(const f32x4*)(vb + av.y);
      f32x4 g10 = *(const f32x4*)(vb + av.z);
      f32x4 g11 = *(const f32x4*)(vb + av.w);
      acc += wv.x * g00;
      acc += wv.y * g01;
      acc += wv.z * g10;
      acc += wv.w * g11;
    }
    uint4 pk;
    ushort_t h16, l16;
    bsplit(acc[0], h16, l16); pk.x = (uint_t)h16 | ((uint_t)l16 << 16);
    bsplit(acc[1], h16, l16); pk.y = (uint_t)h16 | ((uint_t)l16 << 16);
    bsplit(acc[2], h16, l16); pk.z = (uint_t)h16 | ((uint_t)l16 << 16);
    bsplit(acc[3], h16, l16); pk.w = (uint_t)h16 | ((uint_t)l16 << 16);
    *(uint4*)(midp + (size_t)bq * 256 + n * 32 + c4 * 4) = pk;
  }
}

// ---------------------------------------------------------------------------
// K4: out = mid @ W_out + b_out. A pre-split (packed), B from pre-split tables.
// ---------------------------------------------------------------------------
__global__ __launch_bounds__(256, 3) void k_out(
    const uint_t* __restrict__ midp, const ushort_t* __restrict__ wtb,
    const float* __restrict__ bout, float* __restrict__ out)
{
  __shared__ ushort_t lAh[64][40];
  __shared__ ushort_t lAl[64][40];
  int r0 = blockIdx.x * 64;
  int t = threadIdx.x;
  int wave = t >> 6, lane = t & 63;
  int l15 = lane & 15, l4 = lane >> 4;
  int n0 = wave * 64;

  f32x4 acc[4][4];
  #pragma unroll
  for (int m = 0; m < 4; ++m)
    #pragma unroll
    for (int n = 0; n < 4; ++n) acc[m][n] = (f32x4){0.f, 0.f, 0.f, 0.f};

  for (int s = 0; s < 8; ++s) {
    int k0 = s * 32;
    s16x8 bh[4], bl[4];
    #pragma unroll
    for (int n = 0; n < 4; ++n) {
      int col = n0 + n * 16 + l15;
      bh[n] = *(const s16x8*)(wtb + (size_t)col * 256 + k0 + l4 * 8);
      bl[n] = *(const s16x8*)(wtb + 65536 + (size_t)col * 256 + k0 + l4 * 8);
    }
    #pragma unroll
    for (int i = 0; i < 2; ++i) {
      int u = i * 256 + t;
      int row = u >> 3, kq = u & 7;
      uint4 v = *(const uint4*)(midp + (size_t)(r0 + row) * DIM + k0 + kq * 4);
      uint_t a0 = v.x, a1 = v.y, a2 = v.z, a3 = v.w;
      *(uint_t*)&lAh[row][kq * 4]     = (a0 & 0xffffu) | ((a1 & 0xffffu) << 16);
      *(uint_t*)&lAh[row][kq * 4 + 2] = (a2 & 0xffffu) | ((a3 & 0xffffu) << 16);
      *(uint_t*)&lAl[row][kq * 4]     = (a0 >> 16) | (a1 & 0xffff0000u);
      *(uint_t*)&lAl[row][kq * 4 + 2] = (a2 >> 16) | (a3 & 0xffff0000u);
    }
    __syncthreads();
    s16x8 ah[4], al[4];
    #pragma unroll
    for (int m = 0; m < 4; ++m) {
      ah[m] = *(const s16x8*)&lAh[m * 16 + l15][l4 * 8];
      al[m] = *(const s16x8*)&lAl[m * 16 + l15][l4 * 8];
    }
    #pragma unroll
    for (int n = 0; n < 4; ++n)
      #pragma unroll
      for (int m = 0; m < 4; ++m) {
        acc[m][n] = __builtin_amdgcn_mfma_f32_16x16x32_bf16(ah[m], bh[n], acc[m][n], 0, 0, 0);
        acc[m][n] = __builtin_amdgcn_mfma_f32_16x16x32_bf16(al[m], bh[n], acc[m][n], 0, 0, 0);
        acc[m][n] = __builtin_amdgcn_mfma_f32_16x16x32_bf16(ah[m], bl[n], acc[m][n], 0, 0, 0);
      }
    __syncthreads();
  }
  #pragma unroll
  for (int m = 0; m < 4; ++m)
    #pragma unroll
    for (int n = 0; n < 4; ++n) {
      int col = n0 + n * 16 + l15;
      float bias = bout[col];
      #pragma unroll
      for (int i = 0; i < 4; ++i)
        out[(size_t)(r0 + m * 16 + l4 * 4 + i) * DIM + col] = acc[m][n][i] + bias;
    }
}

extern "C" void kernel_launch(void* const* d_in, const int* in_sizes, int n_in,
                              void* d_out, int out_size, void* d_ws, size_t ws_size,
                              hipStream_t stream) {
  const float* query = (const float*)d_in[0];
  const float* refp  = (const float*)d_in[1];
  const float* value = (const float*)d_in[2];
  const float* Woff  = (const float*)d_in[3];
  const float* boff  = (const float*)d_in[4];
  const float* Wattn = (const float*)d_in[5];
  const float* battn = (const float*)d_in[6];
  const float* Wv    = (const float*)d_in[7];
  const float* bv    = (const float*)d_in[8];
  const float* Wout  = (const float*)d_in[9];
  const float* bout  = (const float*)d_in[10];
  float* out = (float*)d_out;
  ushort_t* wbuf = (ushort_t*)d_out;    // Wv/Woffattn tables; dead before k_out

  float* ws      = (float*)d_ws;
  float* vv      = ws;                                  // 22,020,096 f (88 MB)
  float* offattn = ws + 22020096;                       //  9,437,184 f (37.7 MB)
  uint_t* midp   = (uint_t*)(ws + 22020096 + 9437184);  //  8,388,608 u32 (33.5 MB)
  ushort_t* wtb  = (ushort_t*)ws;       // Wout tables, reuse vv region post-sample

  hipLaunchKernelGGL(k_wsplit,  dim3(544),   dim3(256), 0, stream, Wv, Woff, Wattn, wbuf);
  hipLaunchKernelGGL(k_vproj,   dim3(1344),  dim3(256), 0, stream, value, wbuf, bv, vv);
  hipLaunchKernelGGL(k_offattn, dim3(512),   dim3(384), 0, stream, query, wbuf, boff, battn, offattn);
  hipLaunchKernelGGL(k_sample,  dim3(4096),  dim3(256), 0, stream, offattn, refp, vv, midp);
  hipLaunchKernelGGL(k_wsplit2, dim3(256),   dim3(256), 0, stream, Wout, wtb);
  hipLaunchKernelGGL(k_out,     dim3(512),   dim3(256), 0, stream, midp, wtb, bout, out);
}

// Round 6
// 342.168 us; speedup vs baseline: 2.1955x; 1.0339x over previous
//
#include <hip/hip_runtime.h>
#include <math.h>

#define LV 21504
#define LQ 8192
#define BS 4
#define NHD 8
#define HD 32
#define DIM 256

typedef __attribute__((ext_vector_type(4))) float f32x4;
typedef __attribute__((ext_vector_type(8))) short s16x8;
typedef unsigned short ushort_t;
typedef unsigned int uint_t;

// round-to-nearest-even bf16 split: f ~= hi + lo (each bf16)
__device__ __forceinline__ void bsplit(float f, ushort_t& h, ushort_t& l) {
  uint_t u = __float_as_uint(f);
  uint_t hr = (u + 0x7fffu + ((u >> 16) & 1u)) >> 16;
  h = (ushort_t)hr;
  float fh = __uint_as_float(hr << 16);
  float fl = f - fh;
  uint_t v = __float_as_uint(fl);
  l = (ushort_t)((v + 0x7fffu + ((v >> 16) & 1u)) >> 16);
}

__device__ __forceinline__ uint_t bf16rne(float f) {
  uint_t u = __float_as_uint(f);
  return (u + 0x7fffu + ((u >> 16) & 1u)) >> 16;
}

// ---------------------------------------------------------------------------
// K0: split+transpose Wv / Woffattn into bf16 hi/lo [col][k] tables in d_out.
// ---------------------------------------------------------------------------
__global__ __launch_bounds__(256) void k_wsplit(
    const float* __restrict__ Wv, const float* __restrict__ Woff,
    const float* __restrict__ Wattn, ushort_t* __restrict__ wbuf)
{
  int c = blockIdx.x;      // 0..543
  int k = threadIdx.x;     // 0..255
  float w;
  ushort_t *dh, *dl;
  if (c < 256) {
    w = Wv[(size_t)k * 256 + c];
    dh = wbuf + (size_t)c * 256 + k;
    dl = wbuf + 65536 + (size_t)c * 256 + k;
  } else {
    int co = c - 256;      // 0..287
    w = (co < 192) ? Woff[(size_t)k * 192 + co] : Wattn[(size_t)k * 96 + (co - 192)];
    dh = wbuf + 131072 + (size_t)co * 256 + k;
    dl = wbuf + 204800 + (size_t)co * 256 + k;
  }
  ushort_t h, l;
  bsplit(w, h, l);
  *dh = h; *dl = l;
}

// K0b: split Wout into tables in the vv region (dead after k_sample).
__global__ __launch_bounds__(256) void k_wsplit2(
    const float* __restrict__ Wout, ushort_t* __restrict__ tb)
{
  int c = blockIdx.x;      // 0..255
  int k = threadIdx.x;     // 0..255
  float w = Wout[(size_t)k * 256 + c];
  ushort_t h, l;
  bsplit(w, h, l);
  tb[(size_t)c * 256 + k] = h;
  tb[65536 + (size_t)c * 256 + k] = l;
}

// ---------------------------------------------------------------------------
// K1: v = value @ W_v + b_v  ->  view-transposed vv (bf16), MFMA bf16x3.
// BK=64, double-buffered LDS, register prefetch of next A-tile: one barrier
// per K-step; vmcnt wait for prefetch sits after the MFMA cluster.
// ---------------------------------------------------------------------------
__global__ __launch_bounds__(256, 3) void k_vproj(
    const float* __restrict__ value, const ushort_t* __restrict__ wbuf,
    const float* __restrict__ bv, ushort_t* __restrict__ vvb)
{
  __shared__ ushort_t lA[2][2][64][72];   // [buf][hi/lo][row][k], 36.9 KB

  int bid = blockIdx.x;
  int b = bid / 336, rem = bid % 336;
  int l, mp;
  if (rem < 256)      { l = 0; mp = rem; }
  else if (rem < 320) { l = 1; mp = rem - 256; }
  else                { l = 2; mp = rem - 320; }
  const int startl[3] = {0, 16384, 20480};
  const int hwd[3]    = {512, 128, 32};
  int start = startl[l], hd32 = hwd[l], m0 = mp * 2;

  int t = threadIdx.x;
  int wave = t >> 6, lane = t & 63;
  int l15 = lane & 15, l4 = lane >> 4;
  int n0 = wave * 64;

  const float* Ab = value + (size_t)b * LV * DIM;
  int r0s = t >> 4, kq = t & 15;     // staging: rows r0s+16j, k-quad kq
  const float* aptr[4];
  #pragma unroll
  for (int j = 0; j < 4; ++j) {
    int row = r0s + 16 * j;
    aptr[j] = Ab + (size_t)(start + (row & 31) * hd32 + m0 + (row >> 5)) * DIM + kq * 4;
  }

  f32x4 acc[4][4];
  #pragma unroll
  for (int m = 0; m < 4; ++m)
    #pragma unroll
    for (int n = 0; n < 4; ++n) acc[m][n] = (f32x4){0.f, 0.f, 0.f, 0.f};

  float4 pf[4];
  #pragma unroll
  for (int j = 0; j < 4; ++j) pf[j] = *(const float4*)(aptr[j]);

  // stage step 0 into buf 0
  #pragma unroll
  for (int j = 0; j < 4; ++j) {
    int row = r0s + 16 * j;
    float a[4] = {pf[j].x, pf[j].y, pf[j].z, pf[j].w};
    ushort_t hh[4], ll[4];
    #pragma unroll
    for (int q = 0; q < 4; ++q) bsplit(a[q], hh[q], ll[q]);
    uint2 uh, ul;
    uh.x = (uint_t)hh[0] | ((uint_t)hh[1] << 16);
    uh.y = (uint_t)hh[2] | ((uint_t)hh[3] << 16);
    ul.x = (uint_t)ll[0] | ((uint_t)ll[1] << 16);
    ul.y = (uint_t)ll[2] | ((uint_t)ll[3] << 16);
    *(uint2*)&lA[0][0][row][kq * 4] = uh;
    *(uint2*)&lA[0][1][row][kq * 4] = ul;
  }
  __syncthreads();

  int cur = 0;
  for (int s = 0; s < 4; ++s) {
    if (s < 3) {
      #pragma unroll
      for (int j = 0; j < 4; ++j) pf[j] = *(const float4*)(aptr[j] + (s + 1) * 64);
    }
    #pragma unroll
    for (int c = 0; c < 2; ++c) {
      int k0 = s * 64 + c * 32;
      s16x8 bh[4], bl[4];
      #pragma unroll
      for (int n = 0; n < 4; ++n) {
        int col = n0 + n * 16 + l15;
        bh[n] = *(const s16x8*)(wbuf + (size_t)col * 256 + k0 + l4 * 8);
        bl[n] = *(const s16x8*)(wbuf + 65536 + (size_t)col * 256 + k0 + l4 * 8);
      }
      s16x8 ah[4], al[4];
      #pragma unroll
      for (int m = 0; m < 4; ++m) {
        ah[m] = *(const s16x8*)&lA[cur][0][m * 16 + l15][c * 32 + l4 * 8];
        al[m] = *(const s16x8*)&lA[cur][1][m * 16 + l15][c * 32 + l4 * 8];
      }
      #pragma unroll
      for (int n = 0; n < 4; ++n)
        #pragma unroll
        for (int m = 0; m < 4; ++m) {
          acc[m][n] = __builtin_amdgcn_mfma_f32_16x16x32_bf16(ah[m], bh[n], acc[m][n], 0, 0, 0);
          acc[m][n] = __builtin_amdgcn_mfma_f32_16x16x32_bf16(al[m], bh[n], acc[m][n], 0, 0, 0);
          acc[m][n] = __builtin_amdgcn_mfma_f32_16x16x32_bf16(ah[m], bl[n], acc[m][n], 0, 0, 0);
        }
    }
    if (s < 3) {
      #pragma unroll
      for (int j = 0; j < 4; ++j) {
        int row = r0s + 16 * j;
        float a[4] = {pf[j].x, pf[j].y, pf[j].z, pf[j].w};
        ushort_t hh[4], ll[4];
        #pragma unroll
        for (int q = 0; q < 4; ++q) bsplit(a[q], hh[q], ll[q]);
        uint2 uh, ul;
        uh.x = (uint_t)hh[0] | ((uint_t)hh[1] << 16);
        uh.y = (uint_t)hh[2] | ((uint_t)hh[3] << 16);
        ul.x = (uint_t)ll[0] | ((uint_t)ll[1] << 16);
        ul.y = (uint_t)ll[2] | ((uint_t)ll[3] << 16);
        *(uint2*)&lA[cur ^ 1][0][row][kq * 4] = uh;
        *(uint2*)&lA[cur ^ 1][1][row][kq * 4] = ul;
      }
    }
    __syncthreads();
    cur ^= 1;
  }

  // epilogue: bias + bf16-RNE + scatter into view-transposed vv (8B stores)
  #pragma unroll
  for (int m = 0; m < 4; ++m) {
    int d = (m & 1) * 16 + l4 * 4;
    int mloc = m0 + (m >> 1);
    #pragma unroll
    for (int n = 0; n < 4; ++n) {
      int col = n0 + n * 16 + l15;
      int g = col >> 5, j = col & 31;
      float bias = bv[col];
      f32x4 o = acc[m][n];
      uint_t h0 = bf16rne(o[0] + bias), h1 = bf16rne(o[1] + bias);
      uint_t h2 = bf16rne(o[2] + bias), h3 = bf16rne(o[3] + bias);
      uint2 pk;
      pk.x = h0 | (h1 << 16);
      pk.y = h2 | (h3 << 16);
      ushort_t* dst = vvb + (((size_t)(b * NHD + g) * LV + start + (size_t)mloc * 32 + j) * 32 + d);
      *(uint2*)dst = pk;
    }
  }
}

// ---------------------------------------------------------------------------
// K2: offattn = query @ [W_off | W_attn] + bias.
// ---------------------------------------------------------------------------
__global__ __launch_bounds__(384, 3) void k_offattn(
    const float* __restrict__ query, const ushort_t* __restrict__ wbuf,
    const float* __restrict__ boff, const float* __restrict__ battn,
    float* __restrict__ offattn)
{
  __shared__ ushort_t lAh[64][40];
  __shared__ ushort_t lAl[64][40];
  int r0 = blockIdx.x * 64;
  int t = threadIdx.x;
  int wave = t >> 6, lane = t & 63;
  int l15 = lane & 15, l4 = lane >> 4;
  int n0 = wave * 48;
  const ushort_t* wh = wbuf + 131072;
  const ushort_t* wl = wbuf + 204800;

  f32x4 acc[4][3];
  #pragma unroll
  for (int m = 0; m < 4; ++m)
    #pragma unroll
    for (int n = 0; n < 3; ++n) acc[m][n] = (f32x4){0.f, 0.f, 0.f, 0.f};

  for (int s = 0; s < 8; ++s) {
    int k0 = s * 32;
    s16x8 bh[3], bl[3];
    #pragma unroll
    for (int n = 0; n < 3; ++n) {
      int col = n0 + n * 16 + l15;
      bh[n] = *(const s16x8*)(wh + (size_t)col * 256 + k0 + l4 * 8);
      bl[n] = *(const s16x8*)(wl + (size_t)col * 256 + k0 + l4 * 8);
    }
    #pragma unroll
    for (int i = 0; i < 2; ++i) {
      int u = i * 384 + t;
      if (u < 512) {
        int row = u >> 3, kq = u & 7;
        float4 v = *(const float4*)(query + (size_t)(r0 + row) * DIM + k0 + kq * 4);
        float a0[4] = {v.x, v.y, v.z, v.w};
        ushort_t hh[4], ll[4];
        #pragma unroll
        for (int j = 0; j < 4; ++j) bsplit(a0[j], hh[j], ll[j]);
        *(uint_t*)&lAh[row][kq * 4]     = (uint_t)hh[0] | ((uint_t)hh[1] << 16);
        *(uint_t*)&lAh[row][kq * 4 + 2] = (uint_t)hh[2] | ((uint_t)hh[3] << 16);
        *(uint_t*)&lAl[row][kq * 4]     = (uint_t)ll[0] | ((uint_t)ll[1] << 16);
        *(uint_t*)&lAl[row][kq * 4 + 2] = (uint_t)ll[2] | ((uint_t)ll[3] << 16);
      }
    }
    __syncthreads();
    s16x8 ah[4], al[4];
    #pragma unroll
    for (int m = 0; m < 4; ++m) {
      ah[m] = *(const s16x8*)&lAh[m * 16 + l15][l4 * 8];
      al[m] = *(const s16x8*)&lAl[m * 16 + l15][l4 * 8];
    }
    #pragma unroll
    for (int n = 0; n < 3; ++n)
      #pragma unroll
      for (int m = 0; m < 4; ++m) {
        acc[m][n] = __builtin_amdgcn_mfma_f32_16x16x32_bf16(ah[m], bh[n], acc[m][n], 0, 0, 0);
        acc[m][n] = __builtin_amdgcn_mfma_f32_16x16x32_bf16(al[m], bh[n], acc[m][n], 0, 0, 0);
        acc[m][n] = __builtin_amdgcn_mfma_f32_16x16x32_bf16(ah[m], bl[n], acc[m][n], 0, 0, 0);
      }
    __syncthreads();
  }
  #pragma unroll
  for (int m = 0; m < 4; ++m)
    #pragma unroll
    for (int n = 0; n < 3; ++n) {
      int col = n0 + n * 16 + l15;
      float bias = (col < 192) ? boff[col] : battn[col - 192];
      #pragma unroll
      for (int i = 0; i < 4; ++i)
        offattn[(size_t)(r0 + m * 16 + l4 * 4 + i) * 288 + col] = acc[m][n][i] + bias;
    }
}

// ---------------------------------------------------------------------------
// K3: sampler, 3-phase, bf16 vv gathers (64B per spatial cell).
// ---------------------------------------------------------------------------
__global__ __launch_bounds__(256) void k_sample(
    const float* __restrict__ offattn, const float* __restrict__ refp,
    const ushort_t* __restrict__ vvb, uint_t* __restrict__ midp)
{
  __shared__ float4 metaw[64][13];
  __shared__ uint4  metaa[64][13];
  __shared__ float  smx[64], sinv[64];

  int t = threadIdx.x;
  int e0 = blockIdx.x * 64;

  // ---- A0: softmax stats ----
  {
    int it = t >> 2, j = t & 3;
    int e = e0 + it;
    int n = e & 7, bq = e >> 3;
    const float* lgp = offattn + (size_t)bq * 288 + 192 + n * 12;
    float l0 = lgp[j], l1 = lgp[j + 4], l2 = lgp[j + 8];
    float m = fmaxf(fmaxf(l0, l1), l2);
    m = fmaxf(m, __shfl_xor(m, 1));
    m = fmaxf(m, __shfl_xor(m, 2));
    float s = __expf(l0 - m) + __expf(l1 - m) + __expf(l2 - m);
    s += __shfl_xor(s, 1);
    s += __shfl_xor(s, 2);
    if (j == 0) { smx[it] = m; sinv[it] = 1.f / s; }
  }
  __syncthreads();

  // ---- A: per (item,point) combined weights + byte offsets ----
  const int startl[3] = {0, 16384, 20480};
  const int whl[3]    = {128, 64, 32};
  #pragma unroll
  for (int r = 0; r < 3; ++r) {
    int task = r * 256 + t;          // 0..767
    int it = task / 12, p = task % 12;
    int e = e0 + it;
    int n = e & 7, bq = e >> 3;
    int l = p >> 2;
    int w = whl[l], h = w;
    float fw = (float)w;
    const float* oa = offattn + (size_t)bq * 288;
    float ox = oa[n * 24 + p * 2], oy = oa[n * 24 + p * 2 + 1];
    float lg = oa[192 + n * 12 + p];
    float aw = __expf(lg - smx[it]) * sinv[it];
    float rx = refp[bq * 4], ry = refp[bq * 4 + 1];
    float px = fminf(fmaxf(rx + ox, 0.f), 1.f);
    float py = fminf(fmaxf(ry + oy, 0.f), 1.f);
    float x = px * fw - 0.5f, y = py * fw - 0.5f;
    float x0f = floorf(x), y0f = floorf(y);
    int x0 = (int)x0f, y0 = (int)y0f;
    float wx1 = x - x0f, wy1 = y - y0f;
    float wx0 = 1.f - wx1, wy0 = 1.f - wy1;
    float vx0 = ((uint_t)x0 < (uint_t)w) ? 1.f : 0.f;
    float vx1 = ((uint_t)(x0 + 1) < (uint_t)w) ? 1.f : 0.f;
    float vy0 = ((uint_t)y0 < (uint_t)h) ? 1.f : 0.f;
    float vy1 = ((uint_t)(y0 + 1) < (uint_t)h) ? 1.f : 0.f;
    int xc0 = min(max(x0, 0), w - 1), xc1 = min(max(x0 + 1, 0), w - 1);
    int yc0 = min(max(y0, 0), h - 1), yc1 = min(max(y0 + 1, 0), h - 1);
    int s0 = startl[l];
    uint4 av;
    av.x = (uint_t)(s0 + yc0 * w + xc0) * 64u;
    av.y = (uint_t)(s0 + yc0 * w + xc1) * 64u;
    av.z = (uint_t)(s0 + yc1 * w + xc0) * 64u;
    av.w = (uint_t)(s0 + yc1 * w + xc1) * 64u;
    float4 wv;
    wv.x = aw * wy0 * wx0 * vy0 * vx0;
    wv.y = aw * wy0 * wx1 * vy0 * vx1;
    wv.z = aw * wy1 * wx0 * vy1 * vx0;
    wv.w = aw * wy1 * wx1 * vy1 * vx1;
    metaw[it][p] = wv;
    metaa[it][p] = av;
  }
  __syncthreads();

  // ---- B: 8 lanes/item, 4 bf16 channels each ----
  #pragma unroll
  for (int r = 0; r < 2; ++r) {
    int it = (t >> 3) + r * 32;
    int c4 = t & 7;
    int e = e0 + it;
    int n = e & 7, bq = e >> 3, b = bq >> 13;
    const char* vb = (const char*)vvb + (size_t)(b * NHD + n) * LV * 64 + c4 * 8;
    f32x4 acc = (f32x4){0.f, 0.f, 0.f, 0.f};
    #pragma unroll
    for (int p = 0; p < 12; ++p) {
      float4 wv = metaw[it][p];
      uint4  av = metaa[it][p];
      uint2 g00 = *(const uint2*)(vb + av.x);
      uint2 g01 = *(const uint2*)(vb + av.y);
      uint2 g10 = *(const uint2*)(vb + av.z);
      uint2 g11 = *(const uint2*)(vb + av.w);
      f32x4 f;
      f[0] = __uint_as_float(g00.x << 16); f[1] = __uint_as_float(g00.x & 0xffff0000u);
      f[2] = __uint_as_float(g00.y << 16); f[3] = __uint_as_float(g00.y & 0xffff0000u);
      acc += wv.x * f;
      f[0] = __uint_as_float(g01.x << 16); f[1] = __uint_as_float(g01.x & 0xffff0000u);
      f[2] = __uint_as_float(g01.y << 16); f[3] = __uint_as_float(g01.y & 0xffff0000u);
      acc += wv.y * f;
      f[0] = __uint_as_float(g10.x << 16); f[1] = __uint_as_float(g10.x & 0xffff0000u);
      f[2] = __uint_as_float(g10.y << 16); f[3] = __uint_as_float(g10.y & 0xffff0000u);
      acc += wv.z * f;
      f[0] = __uint_as_float(g11.x << 16); f[1] = __uint_as_float(g11.x & 0xffff0000u);
      f[2] = __uint_as_float(g11.y << 16); f[3] = __uint_as_float(g11.y & 0xffff0000u);
      acc += wv.w * f;
    }
    uint4 pk;
    ushort_t h16, l16;
    bsplit(acc[0], h16, l16); pk.x = (uint_t)h16 | ((uint_t)l16 << 16);
    bsplit(acc[1], h16, l16); pk.y = (uint_t)h16 | ((uint_t)l16 << 16);
    bsplit(acc[2], h16, l16); pk.z = (uint_t)h16 | ((uint_t)l16 << 16);
    bsplit(acc[3], h16, l16); pk.w = (uint_t)h16 | ((uint_t)l16 << 16);
    *(uint4*)(midp + (size_t)bq * 256 + n * 32 + c4 * 4) = pk;
  }
}

// ---------------------------------------------------------------------------
// K4: out = mid @ W_out + b_out. A pre-split (packed), B from pre-split tables.
// ---------------------------------------------------------------------------
__global__ __launch_bounds__(256, 3) void k_out(
    const uint_t* __restrict__ midp, const ushort_t* __restrict__ wtb,
    const float* __restrict__ bout, float* __restrict__ out)
{
  __shared__ ushort_t lAh[64][40];
  __shared__ ushort_t lAl[64][40];
  int r0 = blockIdx.x * 64;
  int t = threadIdx.x;
  int wave = t >> 6, lane = t & 63;
  int l15 = lane & 15, l4 = lane >> 4;
  int n0 = wave * 64;

  f32x4 acc[4][4];
  #pragma unroll
  for (int m = 0; m < 4; ++m)
    #pragma unroll
    for (int n = 0; n < 4; ++n) acc[m][n] = (f32x4){0.f, 0.f, 0.f, 0.f};

  for (int s = 0; s < 8; ++s) {
    int k0 = s * 32;
    s16x8 bh[4], bl[4];
    #pragma unroll
    for (int n = 0; n < 4; ++n) {
      int col = n0 + n * 16 + l15;
      bh[n] = *(const s16x8*)(wtb + (size_t)col * 256 + k0 + l4 * 8);
      bl[n] = *(const s16x8*)(wtb + 65536 + (size_t)col * 256 + k0 + l4 * 8);
    }
    #pragma unroll
    for (int i = 0; i < 2; ++i) {
      int u = i * 256 + t;
      int row = u >> 3, kq = u & 7;
      uint4 v = *(const uint4*)(midp + (size_t)(r0 + row) * DIM + k0 + kq * 4);
      uint_t a0 = v.x, a1 = v.y, a2 = v.z, a3 = v.w;
      *(uint_t*)&lAh[row][kq * 4]     = (a0 & 0xffffu) | ((a1 & 0xffffu) << 16);
      *(uint_t*)&lAh[row][kq * 4 + 2] = (a2 & 0xffffu) | ((a3 & 0xffffu) << 16);
      *(uint_t*)&lAl[row][kq * 4]     = (a0 >> 16) | (a1 & 0xffff0000u);
      *(uint_t*)&lAl[row][kq * 4 + 2] = (a2 >> 16) | (a3 & 0xffff0000u);
    }
    __syncthreads();
    s16x8 ah[4], al[4];
    #pragma unroll
    for (int m = 0; m < 4; ++m) {
      ah[m] = *(const s16x8*)&lAh[m * 16 + l15][l4 * 8];
      al[m] = *(const s16x8*)&lAl[m * 16 + l15][l4 * 8];
    }
    #pragma unroll
    for (int n = 0; n < 4; ++n)
      #pragma unroll
      for (int m = 0; m < 4; ++m) {
        acc[m][n] = __builtin_amdgcn_mfma_f32_16x16x32_bf16(ah[m], bh[n], acc[m][n], 0, 0, 0);
        acc[m][n] = __builtin_amdgcn_mfma_f32_16x16x32_bf16(al[m], bh[n], acc[m][n], 0, 0, 0);
        acc[m][n] = __builtin_amdgcn_mfma_f32_16x16x32_bf16(ah[m], bl[n], acc[m][n], 0, 0, 0);
      }
    __syncthreads();
  }
  #pragma unroll
  for (int m = 0; m < 4; ++m)
    #pragma unroll
    for (int n = 0; n < 4; ++n) {
      int col = n0 + n * 16 + l15;
      float bias = bout[col];
      #pragma unroll
      for (int i = 0; i < 4; ++i)
        out[(size_t)(r0 + m * 16 + l4 * 4 + i) * DIM + col] = acc[m][n][i] + bias;
    }
}

extern "C" void kernel_launch(void* const* d_in, const int* in_sizes, int n_in,
                              void* d_out, int out_size, void* d_ws, size_t ws_size,
                              hipStream_t stream) {
  const float* query = (const float*)d_in[0];
  const float* refp  = (const float*)d_in[1];
  const float* value = (const float*)d_in[2];
  const float* Woff  = (const float*)d_in[3];
  const float* boff  = (const float*)d_in[4];
  const float* Wattn = (const float*)d_in[5];
  const float* battn = (const float*)d_in[6];
  const float* Wv    = (const float*)d_in[7];
  const float* bv    = (const float*)d_in[8];
  const float* Wout  = (const float*)d_in[9];
  const float* bout  = (const float*)d_in[10];
  float* out = (float*)d_out;
  ushort_t* wbuf = (ushort_t*)d_out;    // Wv/Woffattn tables; dead before k_out

  float* ws      = (float*)d_ws;
  ushort_t* vvb  = (ushort_t*)ws;                       // 22,020,096 bf16 (44 MB region reserve 88)
  float* offattn = ws + 22020096;                       //  9,437,184 f (37.7 MB)
  uint_t* midp   = (uint_t*)(ws + 22020096 + 9437184);  //  8,388,608 u32 (33.5 MB)
  ushort_t* wtb  = (ushort_t*)ws;       // Wout tables, reuse vv region post-sample

  hipLaunchKernelGGL(k_wsplit,  dim3(544),   dim3(256), 0, stream, Wv, Woff, Wattn, wbuf);
  hipLaunchKernelGGL(k_vproj,   dim3(1344),  dim3(256), 0, stream, value, wbuf, bv, vvb);
  hipLaunchKernelGGL(k_offattn, dim3(512),   dim3(384), 0, stream, query, wbuf, boff, battn, offattn);
  hipLaunchKernelGGL(k_sample,  dim3(4096),  dim3(256), 0, stream, offattn, refp, vvb, midp);
  hipLaunchKernelGGL(k_wsplit2, dim3(256),   dim3(256), 0, stream, Wout, wtb);
  hipLaunchKernelGGL(k_out,     dim3(512),   dim3(256), 0, stream, midp, wtb, bout, out);
}

// Round 8
// 334.206 us; speedup vs baseline: 2.2478x; 1.0238x over previous
//
#include <hip/hip_runtime.h>
#include <math.h>

#define LV 21504
#define LQ 8192
#define BS 4
#define NHD 8
#define HD 32
#define DIM 256

typedef __attribute__((ext_vector_type(4))) float f32x4;
typedef __attribute__((ext_vector_type(8))) short s16x8;
typedef unsigned short ushort_t;
typedef unsigned int uint_t;

// round-to-nearest-even bf16 split: f ~= hi + lo (each bf16)
__device__ __forceinline__ void bsplit(float f, ushort_t& h, ushort_t& l) {
  uint_t u = __float_as_uint(f);
  uint_t hr = (u + 0x7fffu + ((u >> 16) & 1u)) >> 16;
  h = (ushort_t)hr;
  float fh = __uint_as_float(hr << 16);
  float fl = f - fh;
  uint_t v = __float_as_uint(fl);
  l = (ushort_t)((v + 0x7fffu + ((v >> 16) & 1u)) >> 16);
}

__device__ __forceinline__ uint_t bf16rne(float f) {
  uint_t u = __float_as_uint(f);
  return (u + 0x7fffu + ((u >> 16) & 1u)) >> 16;
}

// ---------------------------------------------------------------------------
// K0: split+transpose Wv / Woffattn into bf16 hi/lo [col][k] tables in d_out.
// ---------------------------------------------------------------------------
__global__ __launch_bounds__(256) void k_wsplit(
    const float* __restrict__ Wv, const float* __restrict__ Woff,
    const float* __restrict__ Wattn, ushort_t* __restrict__ wbuf)
{
  int c = blockIdx.x;      // 0..543
  int k = threadIdx.x;     // 0..255
  float w;
  ushort_t *dh, *dl;
  if (c < 256) {
    w = Wv[(size_t)k * 256 + c];
    dh = wbuf + (size_t)c * 256 + k;
    dl = wbuf + 65536 + (size_t)c * 256 + k;
  } else {
    int co = c - 256;      // 0..287
    w = (co < 192) ? Woff[(size_t)k * 192 + co] : Wattn[(size_t)k * 96 + (co - 192)];
    dh = wbuf + 131072 + (size_t)co * 256 + k;
    dl = wbuf + 204800 + (size_t)co * 256 + k;
  }
  ushort_t h, l;
  bsplit(w, h, l);
  *dh = h; *dl = l;
}

// K0b: split Wout into tables in the vv region (dead after k_sample).
__global__ __launch_bounds__(256) void k_wsplit2(
    const float* __restrict__ Wout, ushort_t* __restrict__ tb)
{
  int c = blockIdx.x;      // 0..255
  int k = threadIdx.x;     // 0..255
  float w = Wout[(size_t)k * 256 + c];
  ushort_t h, l;
  bsplit(w, h, l);
  tb[(size_t)c * 256 + k] = h;
  tb[65536 + (size_t)c * 256 + k] = l;
}

// ---------------------------------------------------------------------------
// K1: v = value @ W_v + b_v  ->  view-transposed vv (bf16), MFMA bf16x3.
// 512 threads = 8 waves, per-wave tile M64xN32. Single-buffer LDS (18.4 KB).
// Per K-step: B-loads FIRST, pf A-loads LAST (vmcnt retires in order, so
// B-waits leave pf in flight; pf drains after the MFMA cluster), 2 barriers.
// Epilogue pairs the two 32B half-lines of each 64B line back-to-back.
// ---------------------------------------------------------------------------
__global__ __launch_bounds__(512, 4) void k_vproj(
    const float* __restrict__ value, const ushort_t* __restrict__ wbuf,
    const float* __restrict__ bv, ushort_t* __restrict__ vvb)
{
  __shared__ ushort_t lA[2][64][72];   // [hi/lo][row][k 64+8 pad] = 18,432 B

  int bid = blockIdx.x;
  int b = bid / 336, rem = bid % 336;
  int l, mp;
  if (rem < 256)      { l = 0; mp = rem; }
  else if (rem < 320) { l = 1; mp = rem - 256; }
  else                { l = 2; mp = rem - 320; }
  const int startl[3] = {0, 16384, 20480};
  const int hwd[3]    = {512, 128, 32};
  int start = startl[l], hd32 = hwd[l], m0 = mp * 2;

  int t = threadIdx.x;
  int wave = t >> 6, lane = t & 63;
  int l15 = lane & 15, l4 = lane >> 4;
  int n0 = wave * 32;

  // staging role: thread -> row (0..63), kq (0..7); two float4 per step
  int srow = t >> 3, kq = t & 7;
  const float* ap = value + (size_t)b * LV * DIM
                  + (size_t)(start + (srow & 31) * hd32 + m0 + (srow >> 5)) * DIM + kq * 4;

  f32x4 acc[4][2];
  #pragma unroll
  for (int m = 0; m < 4; ++m)
    #pragma unroll
    for (int n = 0; n < 2; ++n) acc[m][n] = (f32x4){0.f, 0.f, 0.f, 0.f};

  // prologue: stage step 0
  {
    float4 p0 = *(const float4*)(ap);
    float4 p1 = *(const float4*)(ap + 32);
    float a0[4] = {p0.x, p0.y, p0.z, p0.w};
    float a1[4] = {p1.x, p1.y, p1.z, p1.w};
    ushort_t hh[4], ll[4];
    uint2 uh, ul;
    #pragma unroll
    for (int q = 0; q < 4; ++q) bsplit(a0[q], hh[q], ll[q]);
    uh.x = (uint_t)hh[0] | ((uint_t)hh[1] << 16);
    uh.y = (uint_t)hh[2] | ((uint_t)hh[3] << 16);
    ul.x = (uint_t)ll[0] | ((uint_t)ll[1] << 16);
    ul.y = (uint_t)ll[2] | ((uint_t)ll[3] << 16);
    *(uint2*)&lA[0][srow][kq * 4] = uh;
    *(uint2*)&lA[1][srow][kq * 4] = ul;
    #pragma unroll
    for (int q = 0; q < 4; ++q) bsplit(a1[q], hh[q], ll[q]);
    uh.x = (uint_t)hh[0] | ((uint_t)hh[1] << 16);
    uh.y = (uint_t)hh[2] | ((uint_t)hh[3] << 16);
    ul.x = (uint_t)ll[0] | ((uint_t)ll[1] << 16);
    ul.y = (uint_t)ll[2] | ((uint_t)ll[3] << 16);
    *(uint2*)&lA[0][srow][32 + kq * 4] = uh;
    *(uint2*)&lA[1][srow][32 + kq * 4] = ul;
  }
  __syncthreads();

  for (int s = 0; s < 4; ++s) {
    int k0 = s * 64;
    // 1) B fragments for the whole step (issued FIRST)
    s16x8 bh[2][2], bl[2][2];   // [c][n]
    #pragma unroll
    for (int c = 0; c < 2; ++c)
      #pragma unroll
      for (int n = 0; n < 2; ++n) {
        int col = n0 + n * 16 + l15;
        int kk = k0 + c * 32 + l4 * 8;
        bh[c][n] = *(const s16x8*)(wbuf + (size_t)col * 256 + kk);
        bl[c][n] = *(const s16x8*)(wbuf + 65536 + (size_t)col * 256 + kk);
      }
    // 2) prefetch next A-tile (issued LAST -> B-waits don't drain it)
    float4 p0, p1;
    if (s < 3) {
      p0 = *(const float4*)(ap + (s + 1) * 64);
      p1 = *(const float4*)(ap + (s + 1) * 64 + 32);
    }
    // 3) MFMA clusters (A frags from LDS per c-half)
    #pragma unroll
    for (int c = 0; c < 2; ++c) {
      s16x8 ah[4], al[4];
      #pragma unroll
      for (int m = 0; m < 4; ++m) {
        ah[m] = *(const s16x8*)&lA[0][m * 16 + l15][c * 32 + l4 * 8];
        al[m] = *(const s16x8*)&lA[1][m * 16 + l15][c * 32 + l4 * 8];
      }
      #pragma unroll
      for (int n = 0; n < 2; ++n)
        #pragma unroll
        for (int m = 0; m < 4; ++m) {
          acc[m][n] = __builtin_amdgcn_mfma_f32_16x16x32_bf16(ah[m], bh[c][n], acc[m][n], 0, 0, 0);
          acc[m][n] = __builtin_amdgcn_mfma_f32_16x16x32_bf16(al[m], bh[c][n], acc[m][n], 0, 0, 0);
          acc[m][n] = __builtin_amdgcn_mfma_f32_16x16x32_bf16(ah[m], bl[c][n], acc[m][n], 0, 0, 0);
        }
    }
    __syncthreads();   // everyone done reading lA
    if (s < 3) {
      // 4) drain pf (hidden under MFMAs), split, rewrite single buffer
      float a0[4] = {p0.x, p0.y, p0.z, p0.w};
      float a1[4] = {p1.x, p1.y, p1.z, p1.w};
      ushort_t hh[4], ll[4];
      uint2 uh, ul;
      #pragma unroll
      for (int q = 0; q < 4; ++q) bsplit(a0[q], hh[q], ll[q]);
      uh.x = (uint_t)hh[0] | ((uint_t)hh[1] << 16);
      uh.y = (uint_t)hh[2] | ((uint_t)hh[3] << 16);
      ul.x = (uint_t)ll[0] | ((uint_t)ll[1] << 16);
      ul.y = (uint_t)ll[2] | ((uint_t)ll[3] << 16);
      *(uint2*)&lA[0][srow][kq * 4] = uh;
      *(uint2*)&lA[1][srow][kq * 4] = ul;
      #pragma unroll
      for (int q = 0; q < 4; ++q) bsplit(a1[q], hh[q], ll[q]);
      uh.x = (uint_t)hh[0] | ((uint_t)hh[1] << 16);
      uh.y = (uint_t)hh[2] | ((uint_t)hh[3] << 16);
      ul.x = (uint_t)ll[0] | ((uint_t)ll[1] << 16);
      ul.y = (uint_t)ll[2] | ((uint_t)ll[3] << 16);
      *(uint2*)&lA[0][srow][32 + kq * 4] = uh;
      *(uint2*)&lA[1][srow][32 + kq * 4] = ul;
      __syncthreads();
    }
  }

  // epilogue: bias + bf16 + scatter; m-pairs (same 64B line) back-to-back
  #pragma unroll
  for (int n = 0; n < 2; ++n) {
    int col = n0 + n * 16 + l15;
    int g = col >> 5, j = col & 31;
    float bias = bv[col];
    ushort_t* base = vvb + ((size_t)(b * NHD + g) * LV + start) * 32;
    #pragma unroll
    for (int m = 0; m < 4; ++m) {
      int d = (m & 1) * 16 + l4 * 4;
      int mloc = m0 + (m >> 1);
      f32x4 o = acc[m][n];
      uint_t h0 = bf16rne(o[0] + bias), h1 = bf16rne(o[1] + bias);
      uint_t h2 = bf16rne(o[2] + bias), h3 = bf16rne(o[3] + bias);
      uint2 pk;
      pk.x = h0 | (h1 << 16);
      pk.y = h2 | (h3 << 16);
      *(uint2*)(base + ((size_t)mloc * 32 + j) * 32 + d) = pk;
    }
  }
}

// ---------------------------------------------------------------------------
// K2: offattn = query @ [W_off | W_attn] + bias.
// ---------------------------------------------------------------------------
__global__ __launch_bounds__(384, 3) void k_offattn(
    const float* __restrict__ query, const ushort_t* __restrict__ wbuf,
    const float* __restrict__ boff, const float* __restrict__ battn,
    float* __restrict__ offattn)
{
  __shared__ ushort_t lAh[64][40];
  __shared__ ushort_t lAl[64][40];
  int r0 = blockIdx.x * 64;
  int t = threadIdx.x;
  int wave = t >> 6, lane = t & 63;
  int l15 = lane & 15, l4 = lane >> 4;
  int n0 = wave * 48;
  const ushort_t* wh = wbuf + 131072;
  const ushort_t* wl = wbuf + 204800;

  f32x4 acc[4][3];
  #pragma unroll
  for (int m = 0; m < 4; ++m)
    #pragma unroll
    for (int n = 0; n < 3; ++n) acc[m][n] = (f32x4){0.f, 0.f, 0.f, 0.f};

  for (int s = 0; s < 8; ++s) {
    int k0 = s * 32;
    s16x8 bh[3], bl[3];
    #pragma unroll
    for (int n = 0; n < 3; ++n) {
      int col = n0 + n * 16 + l15;
      bh[n] = *(const s16x8*)(wh + (size_t)col * 256 + k0 + l4 * 8);
      bl[n] = *(const s16x8*)(wl + (size_t)col * 256 + k0 + l4 * 8);
    }
    #pragma unroll
    for (int i = 0; i < 2; ++i) {
      int u = i * 384 + t;
      if (u < 512) {
        int row = u >> 3, kq = u & 7;
        float4 v = *(const float4*)(query + (size_t)(r0 + row) * DIM + k0 + kq * 4);
        float a0[4] = {v.x, v.y, v.z, v.w};
        ushort_t hh[4], ll[4];
        #pragma unroll
        for (int j = 0; j < 4; ++j) bsplit(a0[j], hh[j], ll[j]);
        *(uint_t*)&lAh[row][kq * 4]     = (uint_t)hh[0] | ((uint_t)hh[1] << 16);
        *(uint_t*)&lAh[row][kq * 4 + 2] = (uint_t)hh[2] | ((uint_t)hh[3] << 16);
        *(uint_t*)&lAl[row][kq * 4]     = (uint_t)ll[0] | ((uint_t)ll[1] << 16);
        *(uint_t*)&lAl[row][kq * 4 + 2] = (uint_t)ll[2] | ((uint_t)ll[3] << 16);
      }
    }
    __syncthreads();
    s16x8 ah[4], al[4];
    #pragma unroll
    for (int m = 0; m < 4; ++m) {
      ah[m] = *(const s16x8*)&lAh[m * 16 + l15][l4 * 8];
      al[m] = *(const s16x8*)&lAl[m * 16 + l15][l4 * 8];
    }
    #pragma unroll
    for (int n = 0; n < 3; ++n)
      #pragma unroll
      for (int m = 0; m < 4; ++m) {
        acc[m][n] = __builtin_amdgcn_mfma_f32_16x16x32_bf16(ah[m], bh[n], acc[m][n], 0, 0, 0);
        acc[m][n] = __builtin_amdgcn_mfma_f32_16x16x32_bf16(al[m], bh[n], acc[m][n], 0, 0, 0);
        acc[m][n] = __builtin_amdgcn_mfma_f32_16x16x32_bf16(ah[m], bl[n], acc[m][n], 0, 0, 0);
      }
    __syncthreads();
  }
  #pragma unroll
  for (int m = 0; m < 4; ++m)
    #pragma unroll
    for (int n = 0; n < 3; ++n) {
      int col = n0 + n * 16 + l15;
      float bias = (col < 192) ? boff[col] : battn[col - 192];
      #pragma unroll
      for (int i = 0; i < 4; ++i)
        offattn[(size_t)(r0 + m * 16 + l4 * 4 + i) * 288 + col] = acc[m][n][i] + bias;
    }
}

// ---------------------------------------------------------------------------
// K3: sampler, 3-phase, bf16 vv gathers (64B per spatial cell).
// ---------------------------------------------------------------------------
__global__ __launch_bounds__(256) void k_sample(
    const float* __restrict__ offattn, const float* __restrict__ refp,
    const ushort_t* __restrict__ vvb, uint_t* __restrict__ midp)
{
  __shared__ float4 metaw[64][13];
  __shared__ uint4  metaa[64][13];
  __shared__ float  smx[64], sinv[64];

  int t = threadIdx.x;
  int e0 = blockIdx.x * 64;

  // ---- A0: softmax stats ----
  {
    int it = t >> 2, j = t & 3;
    int e = e0 + it;
    int n = e & 7, bq = e >> 3;
    const float* lgp = offattn + (size_t)bq * 288 + 192 + n * 12;
    float l0 = lgp[j], l1 = lgp[j + 4], l2 = lgp[j + 8];
    float m = fmaxf(fmaxf(l0, l1), l2);
    m = fmaxf(m, __shfl_xor(m, 1));
    m = fmaxf(m, __shfl_xor(m, 2));
    float s = __expf(l0 - m) + __expf(l1 - m) + __expf(l2 - m);
    s += __shfl_xor(s, 1);
    s += __shfl_xor(s, 2);
    if (j == 0) { smx[it] = m; sinv[it] = 1.f / s; }
  }
  __syncthreads();

  // ---- A: per (item,point) combined weights + byte offsets ----
  const int startl[3] = {0, 16384, 20480};
  const int whl[3]    = {128, 64, 32};
  #pragma unroll
  for (int r = 0; r < 3; ++r) {
    int task = r * 256 + t;          // 0..767
    int it = task / 12, p = task % 12;
    int e = e0 + it;
    int n = e & 7, bq = e >> 3;
    int l = p >> 2;
    int w = whl[l], h = w;
    float fw = (float)w;
    const float* oa = offattn + (size_t)bq * 288;
    float ox = oa[n * 24 + p * 2], oy = oa[n * 24 + p * 2 + 1];
    float lg = oa[192 + n * 12 + p];
    float aw = __expf(lg - smx[it]) * sinv[it];
    float rx = refp[bq * 4], ry = refp[bq * 4 + 1];
    float px = fminf(fmaxf(rx + ox, 0.f), 1.f);
    float py = fminf(fmaxf(ry + oy, 0.f), 1.f);
    float x = px * fw - 0.5f, y = py * fw - 0.5f;
    float x0f = floorf(x), y0f = floorf(y);
    int x0 = (int)x0f, y0 = (int)y0f;
    float wx1 = x - x0f, wy1 = y - y0f;
    float wx0 = 1.f - wx1, wy0 = 1.f - wy1;
    float vx0 = ((uint_t)x0 < (uint_t)w) ? 1.f : 0.f;
    float vx1 = ((uint_t)(x0 + 1) < (uint_t)w) ? 1.f : 0.f;
    float vy0 = ((uint_t)y0 < (uint_t)h) ? 1.f : 0.f;
    float vy1 = ((uint_t)(y0 + 1) < (uint_t)h) ? 1.f : 0.f;
    int xc0 = min(max(x0, 0), w - 1), xc1 = min(max(x0 + 1, 0), w - 1);
    int yc0 = min(max(y0, 0), h - 1), yc1 = min(max(y0 + 1, 0), h - 1);
    int s0 = startl[l];
    uint4 av;
    av.x = (uint_t)(s0 + yc0 * w + xc0) * 64u;
    av.y = (uint_t)(s0 + yc0 * w + xc1) * 64u;
    av.z = (uint_t)(s0 + yc1 * w + xc0) * 64u;
    av.w = (uint_t)(s0 + yc1 * w + xc1) * 64u;
    float4 wv;
    wv.x = aw * wy0 * wx0 * vy0 * vx0;
    wv.y = aw * wy0 * wx1 * vy0 * vx1;
    wv.z = aw * wy1 * wx0 * vy1 * vx0;
    wv.w = aw * wy1 * wx1 * vy1 * vx1;
    metaw[it][p] = wv;
    metaa[it][p] = av;
  }
  __syncthreads();

  // ---- B: 8 lanes/item, 4 bf16 channels each ----
  #pragma unroll
  for (int r = 0; r < 2; ++r) {
    int it = (t >> 3) + r * 32;
    int c4 = t & 7;
    int e = e0 + it;
    int n = e & 7, bq = e >> 3, b = bq >> 13;
    const char* vb = (const char*)vvb + (size_t)(b * NHD + n) * LV * 64 + c4 * 8;
    f32x4 acc = (f32x4){0.f, 0.f, 0.f, 0.f};
    #pragma unroll
    for (int p = 0; p < 12; ++p) {
      float4 wv = metaw[it][p];
      uint4  av = metaa[it][p];
      uint2 g00 = *(const uint2*)(vb + av.x);
      uint2 g01 = *(const uint2*)(vb + av.y);
      uint2 g10 = *(const uint2*)(vb + av.z);
      uint2 g11 = *(const uint2*)(vb + av.w);
      f32x4 f;
      f[0] = __uint_as_float(g00.x << 16); f[1] = __uint_as_float(g00.x & 0xffff0000u);
      f[2] = __uint_as_float(g00.y << 16); f[3] = __uint_as_float(g00.y & 0xffff0000u);
      acc += wv.x * f;
      f[0] = __uint_as_float(g01.x << 16); f[1] = __uint_as_float(g01.x & 0xffff0000u);
      f[2] = __uint_as_float(g01.y << 16); f[3] = __uint_as_float(g01.y & 0xffff0000u);
      acc += wv.y * f;
      f[0] = __uint_as_float(g10.x << 16); f[1] = __uint_as_float(g10.x & 0xffff0000u);
      f[2] = __uint_as_float(g10.y << 16); f[3] = __uint_as_float(g10.y & 0xffff0000u);
      acc += wv.z * f;
      f[0] = __uint_as_float(g11.x << 16); f[1] = __uint_as_float(g11.x & 0xffff0000u);
      f[2] = __uint_as_float(g11.y << 16); f[3] = __uint_as_float(g11.y & 0xffff0000u);
      acc += wv.w * f;
    }
    uint4 pk;
    ushort_t h16, l16;
    bsplit(acc[0], h16, l16); pk.x = (uint_t)h16 | ((uint_t)l16 << 16);
    bsplit(acc[1], h16, l16); pk.y = (uint_t)h16 | ((uint_t)l16 << 16);
    bsplit(acc[2], h16, l16); pk.z = (uint_t)h16 | ((uint_t)l16 << 16);
    bsplit(acc[3], h16, l16); pk.w = (uint_t)h16 | ((uint_t)l16 << 16);
    *(uint4*)(midp + (size_t)bq * 256 + n * 32 + c4 * 4) = pk;
  }
}

// ---------------------------------------------------------------------------
// K4: out = mid @ W_out + b_out. A pre-split (packed), B from pre-split tables.
// ---------------------------------------------------------------------------
__global__ __launch_bounds__(256, 3) void k_out(
    const uint_t* __restrict__ midp, const ushort_t* __restrict__ wtb,
    const float* __restrict__ bout, float* __restrict__ out)
{
  __shared__ ushort_t lAh[64][40];
  __shared__ ushort_t lAl[64][40];
  int r0 = blockIdx.x * 64;
  int t = threadIdx.x;
  int wave = t >> 6, lane = t & 63;
  int l15 = lane & 15, l4 = lane >> 4;
  int n0 = wave * 64;

  f32x4 acc[4][4];
  #pragma unroll
  for (int m = 0; m < 4; ++m)
    #pragma unroll
    for (int n = 0; n < 4; ++n) acc[m][n] = (f32x4){0.f, 0.f, 0.f, 0.f};

  for (int s = 0; s < 8; ++s) {
    int k0 = s * 32;
    s16x8 bh[4], bl[4];
    #pragma unroll
    for (int n = 0; n < 4; ++n) {
      int col = n0 + n * 16 + l15;
      bh[n] = *(const s16x8*)(wtb + (size_t)col * 256 + k0 + l4 * 8);
      bl[n] = *(const s16x8*)(wtb + 65536 + (size_t)col * 256 + k0 + l4 * 8);
    }
    #pragma unroll
    for (int i = 0; i < 2; ++i) {
      int u = i * 256 + t;
      int row = u >> 3, kq = u & 7;
      uint4 v = *(const uint4*)(midp + (size_t)(r0 + row) * DIM + k0 + kq * 4);
      uint_t a0 = v.x, a1 = v.y, a2 = v.z, a3 = v.w;
      *(uint_t*)&lAh[row][kq * 4]     = (a0 & 0xffffu) | ((a1 & 0xffffu) << 16);
      *(uint_t*)&lAh[row][kq * 4 + 2] = (a2 & 0xffffu) | ((a3 & 0xffffu) << 16);
      *(uint_t*)&lAl[row][kq * 4]     = (a0 >> 16) | (a1 & 0xffff0000u);
      *(uint_t*)&lAl[row][kq * 4 + 2] = (a2 >> 16) | (a3 & 0xffff0000u);
    }
    __syncthreads();
    s16x8 ah[4], al[4];
    #pragma unroll
    for (int m = 0; m < 4; ++m) {
      ah[m] = *(const s16x8*)&lAh[m * 16 + l15][l4 * 8];
      al[m] = *(const s16x8*)&lAl[m * 16 + l15][l4 * 8];
    }
    #pragma unroll
    for (int n = 0; n < 4; ++n)
      #pragma unroll
      for (int m = 0; m < 4; ++m) {
        acc[m][n] = __builtin_amdgcn_mfma_f32_16x16x32_bf16(ah[m], bh[n], acc[m][n], 0, 0, 0);
        acc[m][n] = __builtin_amdgcn_mfma_f32_16x16x32_bf16(al[m], bh[n], acc[m][n], 0, 0, 0);
        acc[m][n] = __builtin_amdgcn_mfma_f32_16x16x32_bf16(ah[m], bl[n], acc[m][n], 0, 0, 0);
      }
    __syncthreads();
  }
  #pragma unroll
  for (int m = 0; m < 4; ++m)
    #pragma unroll
    for (int n = 0; n < 4; ++n) {
      int col = n0 + n * 16 + l15;
      float bias = bout[col];
      #pragma unroll
      for (int i = 0; i < 4; ++i)
        out[(size_t)(r0 + m * 16 + l4 * 4 + i) * DIM + col] = acc[m][n][i] + bias;
    }
}

extern "C" void kernel_launch(void* const* d_in, const int* in_sizes, int n_in,
                              void* d_out, int out_size, void* d_ws, size_t ws_size,
                              hipStream_t stream) {
  const float* query = (const float*)d_in[0];
  const float* refp  = (const float*)d_in[1];
  const float* value = (const float*)d_in[2];
  const float* Woff  = (const float*)d_in[3];
  const float* boff  = (const float*)d_in[4];
  const float* Wattn = (const float*)d_in[5];
  const float* battn = (const float*)d_in[6];
  const float* Wv    = (const float*)d_in[7];
  const float* bv    = (const float*)d_in[8];
  const float* Wout  = (const float*)d_in[9];
  const float* bout  = (const float*)d_in[10];
  float* out = (float*)d_out;
  ushort_t* wbuf = (ushort_t*)d_out;    // Wv/Woffattn tables; dead before k_out

  float* ws      = (float*)d_ws;
  ushort_t* vvb  = (ushort_t*)ws;                       // 22,020,096 bf16 (44 MB)
  float* offattn = ws + 22020096;                       //  9,437,184 f (37.7 MB)
  uint_t* midp   = (uint_t*)(ws + 22020096 + 9437184);  //  8,388,608 u32 (33.5 MB)
  ushort_t* wtb  = (ushort_t*)ws;       // Wout tables, reuse vv region post-sample

  hipLaunchKernelGGL(k_wsplit,  dim3(544),   dim3(256), 0, stream, Wv, Woff, Wattn, wbuf);
  hipLaunchKernelGGL(k_vproj,   dim3(1344),  dim3(512), 0, stream, value, wbuf, bv, vvb);
  hipLaunchKernelGGL(k_offattn, dim3(512),   dim3(384), 0, stream, query, wbuf, boff, battn, offattn);
  hipLaunchKernelGGL(k_sample,  dim3(4096),  dim3(256), 0, stream, offattn, refp, vvb, midp);
  hipLaunchKernelGGL(k_wsplit2, dim3(256),   dim3(256), 0, stream, Wout, wtb);
  hipLaunchKernelGGL(k_out,     dim3(512),   dim3(256), 0, stream, midp, wtb, bout, out);
}